// Round 5
// baseline (624.173 us; speedup 1.0000x reference)
//
#include <hip/hip_runtime.h>
#include <stdint.h>

#define ROWS   16384   // B*S
#define KDIM   256
#define DMDIM  512
#define DOUTD  1024
#define BANKN  4096
#define DIND   1024
#define HDIMD  2048
#define FPAD   1024    // max fixup rows
#define SCHUNK 64      // scan chunk length (steps)
#define NCHK   32      // 2048 / SCHUNK chunks per batch
#define KZ1    2       // fixup GEMM1 split-K
#define KZ2    8       // fixup GEMM2 split-K

typedef unsigned int u32;
typedef unsigned short u16;
typedef unsigned char u8;
typedef unsigned long long u64;
typedef _Float16 f16;
typedef _Float16 v8h __attribute__((ext_vector_type(8)));
typedef short    v8s __attribute__((ext_vector_type(8)));
typedef u16      v8u __attribute__((ext_vector_type(8)));
typedef u16      v4u __attribute__((ext_vector_type(4)));
typedef float    v4f __attribute__((ext_vector_type(4)));

// ---------- split helpers: v = hi(f16) + lo(f16)*2^-11; lo stored pre-scaled by 2048 ----------
__device__ __forceinline__ u32 pack_split(float v) {
    _Float16 h = (_Float16)v;
    float r = (v - (float)h) * 2048.0f;     // exact scale; keeps lo in f16 normal range
    _Float16 l = (_Float16)r;
    u16 hs = __builtin_bit_cast(u16, h);
    u16 ls = __builtin_bit_cast(u16, l);
    return (u32)hs | ((u32)ls << 16);
}
__device__ __forceinline__ v8h unpL(uint4 a, uint4 b) {   // main (low 16 bits)
    v8s s1 = __builtin_bit_cast(v8s, a);
    v8s s2 = __builtin_bit_cast(v8s, b);
    v8s lo = __builtin_shufflevector(s1, s2, 0, 2, 4, 6, 8, 10, 12, 14);
    return __builtin_bit_cast(v8h, lo);
}
__device__ __forceinline__ v8h unpH(uint4 a, uint4 b) {   // scaled residual (high 16 bits)
    v8s s1 = __builtin_bit_cast(v8s, a);
    v8s s2 = __builtin_bit_cast(v8s, b);
    v8s hi = __builtin_shufflevector(s1, s2, 1, 3, 5, 7, 9, 11, 13, 15);
    return __builtin_bit_cast(v8h, hi);
}
__device__ __forceinline__ v4f mfma16(v8h a, v8h b, v4f c) {
    return __builtin_amdgcn_mfma_f32_16x16x32_f16(a, b, c, 0, 0, 0);
}
__device__ __forceinline__ void gl_lds16(const u32* g, u32* l) {
    __builtin_amdgcn_global_load_lds(g, l, 16, 0, 0);
}

// ---------------- split-f16 MFMA GEMM, A main-only, B = main+res planes ----------------
// A: [M x K] f16. Bm/Br: [N x K] f16 planes. 128x128 tile, BK=64, 4 waves.
// LDS layout: rows of 64 f16 (128B), 16B slots XOR-swizzled: byte = row*128 + 16*(slot ^ (row&7)).
// Staged via global_load_lds (linear LDS dest) with inverse-swizzled per-lane global source.
// OSPLIT: relu+bias -> f16 out. else: fp32 partial out at Cv + bz*M*N (split-K via gridDim.z).
template<bool OSPLIT>
__global__ __launch_bounds__(256, 2)
void gemm_mfma(const f16* __restrict__ A, const f16* __restrict__ Bm_,
               const f16* __restrict__ Br_, const float* __restrict__ bias,
               void* __restrict__ Cv, int K, int kLen)
{
    __shared__ f16 As[128 * 64];        // 16 KB
    __shared__ f16 Bs[2 * 128 * 64];    // 32 KB (main plane, then res plane)
    const int N = gridDim.x * 128;
    const int M = gridDim.y * 128;

    // XCD-aware remap: blocks sharing an A-panel stay on one XCD
    long gx = gridDim.x, gy = gridDim.y, gz = gridDim.z;
    long flat = ((long)blockIdx.z * gy + blockIdx.y) * gx + blockIdx.x;
    long nb = gx * gy * gz;
    long lid = (flat & 7) * (nb >> 3) + (flat >> 3);
    int bx = (int)(lid % gx);
    long t2 = lid / gx;
    int by = (int)(t2 % gy);
    int bz = (int)(t2 / gy);

    const int m0 = by * 128, n0 = bx * 128;
    const int kStart = bz * kLen;

    const int tid = threadIdx.x;
    const int lane = tid & 63, wv = tid >> 6;
    const int lx = lane & 15, q = lane >> 4;
    const int wm = (wv >> 1) * 64, wn = (wv & 1) * 64;

    // staging: chunk c = tid + r*256 (16B chunks). row = c>>3, slot j = c&7.
    // content for slot j must be global k8 = j ^ (row&7)  (inverse of read-side XOR swizzle).
    const int rowb = tid >> 3;                       // + r*32 per r
    const int k8   = (tid & 7) ^ (rowb & 7);         // r*32 ≡ 0 (mod 8) -> same for all r
    const f16* gA  = A   + (size_t)(m0 + rowb) * K + kStart + k8 * 8;
    const f16* gBm = Bm_ + (size_t)(n0 + rowb) * K + kStart + k8 * 8;
    const f16* gBr = Br_ + (size_t)(n0 + rowb) * K + kStart + k8 * 8;
    f16* lA  = As + (wv * 64) * 8;            // wave-uniform base; +r*2048 f16 per r
    f16* lBm = Bs + (wv * 64) * 8;
    f16* lBr = Bs + 8192 + (wv * 64) * 8;

    // fragment LDS byte offsets: row*128 + ((s*64 + q*16) ^ ((row&7)<<4))
    int aOff[4][2], bOff[4][2];
    #pragma unroll
    for (int i = 0; i < 4; i++) {
        int ra = wm + i * 16 + lx;
        int rb = wn + i * 16 + lx;
        #pragma unroll
        for (int s = 0; s < 2; s++) {
            aOff[i][s] = ra * 128 + ((s * 64 + q * 16) ^ ((ra & 7) << 4));
            bOff[i][s] = rb * 128 + ((s * 64 + q * 16) ^ ((rb & 7) << 4));
        }
    }

    v4f acc1[4][4], acc2[4][4];
    #pragma unroll
    for (int i = 0; i < 4; i++)
        #pragma unroll
        for (int j = 0; j < 4; j++) { v4f z = {0.f, 0.f, 0.f, 0.f}; acc1[i][j] = z; acc2[i][j] = z; }

    for (int kt = 0; kt < kLen; kt += 64) {
        #pragma unroll
        for (int r = 0; r < 4; r++) {
            gl_lds16((const u32*)(gA  + (size_t)r * 32 * K), (u32*)(lA  + r * 2048));
            gl_lds16((const u32*)(gBm + (size_t)r * 32 * K), (u32*)(lBm + r * 2048));
            gl_lds16((const u32*)(gBr + (size_t)r * 32 * K), (u32*)(lBr + r * 2048));
        }
        gA += 64; gBm += 64; gBr += 64;
        __syncthreads();

        #pragma unroll
        for (int s = 0; s < 2; s++) {
            v8h am[4], bm[4], br[4];
            #pragma unroll
            for (int i = 0; i < 4; i++) {
                am[i] = *(const v8h*)((const char*)As + aOff[i][s]);
                bm[i] = *(const v8h*)((const char*)Bs + bOff[i][s]);
                br[i] = *(const v8h*)((const char*)Bs + 16384 + bOff[i][s]);
            }
            #pragma unroll
            for (int mi = 0; mi < 4; mi++)
                #pragma unroll
                for (int ni = 0; ni < 4; ni++) {
                    acc1[mi][ni] = mfma16(am[mi], bm[ni], acc1[mi][ni]);
                    acc2[mi][ni] = mfma16(am[mi], br[ni], acc2[mi][ni]);
                }
        }
        __syncthreads();
    }

    const float RS = 1.0f / 2048.0f;
    #pragma unroll
    for (int mi = 0; mi < 4; mi++) {
        #pragma unroll
        for (int ni = 0; ni < 4; ni++) {
            int col = n0 + wn + ni * 16 + lx;
            #pragma unroll
            for (int r = 0; r < 4; r++) {
                int row = m0 + wm + mi * 16 + q * 4 + r;
                float v = acc1[mi][ni][r] + acc2[mi][ni][r] * RS;
                if (OSPLIT) {
                    v += bias[col];
                    v = fmaxf(v, 0.f);
                    ((u16*)Cv)[(size_t)row * N + col] = __builtin_bit_cast(u16, (_Float16)v);
                } else {
                    ((float*)Cv)[(size_t)bz * M * N + (size_t)row * N + col] = v;
                }
            }
        }
    }
}

// ---------------- split-split 3-MFMA GEMM (round-0 kernel): near-fp32 accuracy ----------------
// A: [M x K] packed u32 (hi,lo). Bt: [N x K] packed u32. 128x128 tile, BK=32.
// BIASF: fp32 out + bias (gridDim.z must be 1). else fp32 partial at Cv + bz*M*N.
template<bool BIASF>
__global__ __launch_bounds__(256, 2)
void gemm_sp3(const u32* __restrict__ A, const u32* __restrict__ Bt,
              const float* __restrict__ bias, float* __restrict__ Cv,
              int K, int kLen)
{
    __shared__ u32 As[4096];   // 1024 chunks * 16B
    __shared__ u32 Bs[4096];
    const int N = gridDim.x * 128;
    const int M = gridDim.y * 128;

    long gx = gridDim.x, gy = gridDim.y, gz = gridDim.z;
    long flat = ((long)blockIdx.z * gy + blockIdx.y) * gx + blockIdx.x;
    long nb = gx * gy * gz;
    long lid = (flat & 7) * (nb >> 3) + (flat >> 3);
    int bx = (int)(lid % gx);
    long t2 = lid / gx;
    int by = (int)(t2 % gy);
    int bz = (int)(t2 / gy);

    const int m0 = by * 128, n0 = bx * 128;
    const int kStart = bz * kLen;

    const int tid = threadIdx.x;
    const int lane = tid & 63, wv = tid >> 6;
    const int lx = lane & 15, q = lane >> 4;
    const int wm = (wv >> 1) * 64, wn = (wv & 1) * 64;

    const u32* gA = A + (size_t)(m0 + (tid >> 6) * 8 + (tid & 7)) * K + kStart + ((tid >> 3) & 7) * 4;
    const u32* gB = Bt + (size_t)(n0 + (tid >> 6) * 8 + (tid & 7)) * K + kStart + ((tid >> 3) & 7) * 4;
    u32* lA = As + (wv * 64) * 4;
    u32* lB = Bs + (wv * 64) * 4;

    int caOff[4], cbOff[4];
    #pragma unroll
    for (int i = 0; i < 4; i++) {
        int m = wm + i * 16 + lx;
        caOff[i] = (((m >> 3) * 64) + q * 16 + (m & 7)) * 4;
        int n = wn + i * 16 + lx;
        cbOff[i] = (((n >> 3) * 64) + q * 16 + (n & 7)) * 4;
    }

    v4f acc1[4][4], acc2[4][4];
    #pragma unroll
    for (int i = 0; i < 4; i++)
        #pragma unroll
        for (int j = 0; j < 4; j++) { v4f z = {0.f, 0.f, 0.f, 0.f}; acc1[i][j] = z; acc2[i][j] = z; }

    for (int kt = 0; kt < kLen; kt += 32) {
        #pragma unroll
        for (int r = 0; r < 4; r++) {
            gl_lds16(gA + (size_t)r * 32 * K, lA + r * 1024);
            gl_lds16(gB + (size_t)r * 32 * K, lB + r * 1024);
        }
        gA += 32; gB += 32;
        __syncthreads();

        v8h am[4], ar[4], bm[4], br[4];
        #pragma unroll
        for (int i = 0; i < 4; i++) {
            uint4 x1 = *(const uint4*)(As + caOff[i]);
            uint4 x2 = *(const uint4*)(As + caOff[i] + 32);
            am[i] = unpL(x1, x2); ar[i] = unpH(x1, x2);
            uint4 y1 = *(const uint4*)(Bs + cbOff[i]);
            uint4 y2 = *(const uint4*)(Bs + cbOff[i] + 32);
            bm[i] = unpL(y1, y2); br[i] = unpH(y1, y2);
        }
        #pragma unroll
        for (int mi = 0; mi < 4; mi++)
            #pragma unroll
            for (int ni = 0; ni < 4; ni++) {
                acc1[mi][ni] = mfma16(am[mi], bm[ni], acc1[mi][ni]);
                acc2[mi][ni] = mfma16(am[mi], br[ni], acc2[mi][ni]);
                acc2[mi][ni] = mfma16(ar[mi], bm[ni], acc2[mi][ni]);
            }
        __syncthreads();
    }

    const float RS = 1.0f / 2048.0f;
    #pragma unroll
    for (int mi = 0; mi < 4; mi++) {
        #pragma unroll
        for (int ni = 0; ni < 4; ni++) {
            int col = n0 + wn + ni * 16 + lx;
            #pragma unroll
            for (int r = 0; r < 4; r++) {
                int row = m0 + wm + mi * 16 + q * 4 + r;
                float v = acc1[mi][ni][r] + acc2[mi][ni][r] * RS;
                if (BIASF) {
                    Cv[(size_t)row * N + col] = v + bias[col];
                } else {
                    Cv[(size_t)bz * M * N + (size_t)row * N + col] = v;
                }
            }
        }
    }
}

// ---------------- elementwise f16 pack of x (main plane only) ----------------
__global__ __launch_bounds__(256)
void packx_k(const float* __restrict__ x, u16* __restrict__ xo, long n8)
{
    long i = (long)blockIdx.x * 256 + threadIdx.x;
    if (i >= n8) return;
    const float4* xp = (const float4*)x;
    float4 a = xp[2 * i], b = xp[2 * i + 1];
    v8u o;
    o[0] = __builtin_bit_cast(u16, (_Float16)a.x);
    o[1] = __builtin_bit_cast(u16, (_Float16)a.y);
    o[2] = __builtin_bit_cast(u16, (_Float16)a.z);
    o[3] = __builtin_bit_cast(u16, (_Float16)a.w);
    o[4] = __builtin_bit_cast(u16, (_Float16)b.x);
    o[5] = __builtin_bit_cast(u16, (_Float16)b.y);
    o[6] = __builtin_bit_cast(u16, (_Float16)b.z);
    o[7] = __builtin_bit_cast(u16, (_Float16)b.w);
    *(v8u*)(xo + i * 8) = o;
}

// ---------------- elementwise split-pack to u32 (hi,lo) ----------------
__global__ __launch_bounds__(256)
void packrow_k(const float* __restrict__ x, u32* __restrict__ xi, long n4)
{
    long i = (long)blockIdx.x * 256 + threadIdx.x;
    if (i >= n4) return;
    float4 v = ((const float4*)x)[i];
    uint4 o;
    o.x = pack_split(v.x); o.y = pack_split(v.y);
    o.z = pack_split(v.z); o.w = pack_split(v.w);
    ((uint4*)xi)[i] = o;
}

// ---------------- transpose + split-pack u32: W[K x N] f32 -> Wt[N x K] u32 ----------------
__global__ __launch_bounds__(256)
void tpack_k(const float* __restrict__ W, u32* __restrict__ Wt, int K, int N)
{
    __shared__ u32 L[32][33];
    int k0 = blockIdx.y * 32, n0 = blockIdx.x * 32;
    int r = threadIdx.x >> 3, c4 = (threadIdx.x & 7) * 4;
    float4 v = *(const float4*)(W + (size_t)(k0 + r) * N + n0 + c4);
    L[r][c4 + 0] = pack_split(v.x);
    L[r][c4 + 1] = pack_split(v.y);
    L[r][c4 + 2] = pack_split(v.z);
    L[r][c4 + 3] = pack_split(v.w);
    __syncthreads();
    uint4 ov;
    ov.x = L[c4 + 0][r]; ov.y = L[c4 + 1][r]; ov.z = L[c4 + 2][r]; ov.w = L[c4 + 3][r];
    *(uint4*)(Wt + (size_t)(n0 + r) * K + k0 + c4) = ov;
}

// ---------------- transpose + split of weights: W[K x N] f32 -> main/res planes [N x K] f16 ----------------
__global__ __launch_bounds__(256)
void tsplit_k(const float* __restrict__ W, u16* __restrict__ Wm, u16* __restrict__ Wr,
              int K, int N)
{
    __shared__ u32 L[32][33];
    int k0 = blockIdx.y * 32, n0 = blockIdx.x * 32;
    int r = threadIdx.x >> 3, c4 = (threadIdx.x & 7) * 4;
    float4 v = *(const float4*)(W + (size_t)(k0 + r) * N + n0 + c4);
    L[r][c4 + 0] = pack_split(v.x);
    L[r][c4 + 1] = pack_split(v.y);
    L[r][c4 + 2] = pack_split(v.z);
    L[r][c4 + 3] = pack_split(v.w);
    __syncthreads();
    u32 o0 = L[c4 + 0][r], o1 = L[c4 + 1][r], o2 = L[c4 + 2][r], o3 = L[c4 + 3][r];
    v4u mo, ro;
    mo[0] = (u16)o0; mo[1] = (u16)o1; mo[2] = (u16)o2; mo[3] = (u16)o3;
    ro[0] = (u16)(o0 >> 16); ro[1] = (u16)(o1 >> 16); ro[2] = (u16)(o2 >> 16); ro[3] = (u16)(o3 >> 16);
    *(v4u*)(Wm + (size_t)(n0 + r) * K + k0 + c4) = mo;
    *(v4u*)(Wr + (size_t)(n0 + r) * K + k0 + c4) = ro;
}

// ---------------- reduce split-K partials + bias -> logits ----------------
__global__ __launch_bounds__(256)
void reduce2_k(const float* __restrict__ part, const float* __restrict__ bias,
               float* __restrict__ outp, int total4, int zStride4, int zc)
{
    int i = blockIdx.x * 256 + threadIdx.x;
    if (i >= total4) return;
    const float4* p = (const float4*)part;
    float4 s = p[i];
    for (int z = 1; z < zc; z++) {
        float4 t = p[(size_t)z * zStride4 + i];
        s.x += t.x; s.y += t.y; s.z += t.z; s.w += t.w;
    }
    float4 b = ((const float4*)bias)[i & 63];
    s.x += b.x; s.y += b.y; s.z += b.z; s.w += b.w;
    ((float4*)outp)[i] = s;
}

// ---------------- generic fp32 GEMM, 64x64 tile (fixup split-K) ----------------
template<bool BT, bool BIAS, bool RELU>
__global__ __launch_bounds__(256)
void gemm64(const float* __restrict__ A, const float* __restrict__ Bm,
            const float* __restrict__ bias, float* __restrict__ C,
            int M, int N, int K, int kLen, const int* __restrict__ mcount)
{
    if (mcount && (int)blockIdx.y * 64 >= *mcount) return;
    __shared__ float As[16][68];
    __shared__ float Bs[16][68];
    const int tid = threadIdx.x;
    const int tx = tid & 15, ty = tid >> 4;
    const int m0 = blockIdx.y * 64;
    const int n0 = blockIdx.x * 64;
    const int z  = blockIdx.z;
    const int kStart = z * kLen;
    float* Cz = C + (size_t)z * M * N;
    float acc[4][4];
    #pragma unroll
    for (int i = 0; i < 4; i++)
        #pragma unroll
        for (int j = 0; j < 4; j++) acc[i][j] = 0.f;

    for (int kt = kStart; kt < kStart + kLen; kt += 16) {
        {
            int m = tid >> 2, kq = tid & 3;
            float4 av = *(const float4*)(A + (size_t)(m0 + m) * K + kt + kq * 4);
            As[kq*4+0][m]=av.x; As[kq*4+1][m]=av.y; As[kq*4+2][m]=av.z; As[kq*4+3][m]=av.w;
        }
        if (BT) {
            int n = tid >> 2, kq = tid & 3;
            float4 bv = *(const float4*)(Bm + (size_t)(n0 + n) * K + kt + kq * 4);
            Bs[kq*4+0][n]=bv.x; Bs[kq*4+1][n]=bv.y; Bs[kq*4+2][n]=bv.z; Bs[kq*4+3][n]=bv.w;
        } else {
            int n4 = tid & 15, kk = tid >> 4;
            float4 bv = *(const float4*)(Bm + (size_t)(kt + kk) * N + n0 + n4 * 4);
            *(float4*)&Bs[kk][n4 * 4] = bv;
        }
        __syncthreads();
        #pragma unroll
        for (int k = 0; k < 16; k++) {
            float4 a0 = *(const float4*)&As[k][ty * 4];
            float4 b0 = *(const float4*)&Bs[k][tx * 4];
            float a[4] = {a0.x, a0.y, a0.z, a0.w};
            float b[4] = {b0.x, b0.y, b0.z, b0.w};
            #pragma unroll
            for (int i = 0; i < 4; i++)
                #pragma unroll
                for (int j = 0; j < 4; j++)
                    acc[i][j] = fmaf(a[i], b[j], acc[i][j]);
        }
        __syncthreads();
    }
    float4 bi = make_float4(0.f,0.f,0.f,0.f);
    if (BIAS) bi = *(const float4*)(bias + n0 + tx * 4);
    #pragma unroll
    for (int i = 0; i < 4; i++) {
        int m = m0 + ty * 4 + i;
        float o0 = acc[i][0]+bi.x, o1 = acc[i][1]+bi.y, o2 = acc[i][2]+bi.z, o3 = acc[i][3]+bi.w;
        if (RELU) { o0=fmaxf(o0,0.f); o1=fmaxf(o1,0.f); o2=fmaxf(o2,0.f); o3=fmaxf(o3,0.f); }
        *(float4*)(Cz + (size_t)m * N + n0 + tx * 4) = make_float4(o0, o1, o2, o3);
    }
}

// ---------------- 1/max(||bank_keys[n]||,1e-12) ----------------
__global__ __launch_bounds__(64)
void invkn_k(const float* __restrict__ keys, float* __restrict__ inv_kn)
{
    int n = blockIdx.x, l = threadIdx.x;
    const float4* r = (const float4*)(keys + (size_t)n * 512);
    float4 a = r[l], b = r[l + 64];
    float s = a.x*a.x + a.y*a.y + a.z*a.z + a.w*a.w
            + b.x*b.x + b.y*b.y + b.z*b.z + b.w*b.w;
    #pragma unroll
    for (int off = 32; off; off >>= 1) s += __shfl_xor(s, off);
    if (l == 0) inv_kn[n] = 1.0f / fmaxf(sqrtf(s), 1e-12f);
}

// ---------------- masked scaled softmax over 4096 slots, per k-row, in place ----------------
__global__ __launch_bounds__(256)
void softmax_k(const float* __restrict__ Mw, const float* __restrict__ inv_kn,
               const float* __restrict__ used, float* __restrict__ sc)
{
    const int k = blockIdx.x, tid = threadIdx.x;
    __shared__ float red[256];
    float m0 = Mw[(size_t)k*512 + tid];
    float m1 = Mw[(size_t)k*512 + 256 + tid];
    red[tid] = m0*m0 + m1*m1;
    __syncthreads();
    for (int s = 128; s > 0; s >>= 1) { if (tid < s) red[tid] += red[tid+s]; __syncthreads(); }
    float scale = 4.0f / fmaxf(sqrtf(red[0]), 1e-12f);
    __syncthreads();
    float vals[16];
    float mx = -3.0e38f;
    #pragma unroll
    for (int j = 0; j < 16; j++) {
        int n = j*256 + tid;
        float v = sc[(size_t)k*4096 + n] * scale * inv_kn[n];
        v = (used[n] > 0.5f) ? v : -1e30f;
        vals[j] = v; mx = fmaxf(mx, v);
    }
    red[tid] = mx; __syncthreads();
    for (int s = 128; s > 0; s >>= 1) { if (tid < s) red[tid] = fmaxf(red[tid], red[tid+s]); __syncthreads(); }
    mx = red[0]; __syncthreads();
    float sum = 0.f;
    #pragma unroll
    for (int j = 0; j < 16; j++) { float e = expf(vals[j] - mx); vals[j] = e; sum += e; }
    red[tid] = sum; __syncthreads();
    for (int s = 128; s > 0; s >>= 1) { if (tid < s) red[tid] += red[tid+s]; __syncthreads(); }
    float inv = 1.0f / red[0];
    #pragma unroll
    for (int j = 0; j < 16; j++) { int n = j*256 + tid; sc[(size_t)k*4096 + n] = vals[j] * inv; }
}

// ---------------- reduce bank split-K partials ----------------
__global__ __launch_bounds__(256)
void redk_k(const float* __restrict__ part, float* __restrict__ outp)
{
    int idx = blockIdx.x * 256 + threadIdx.x;   // 131072 total
    float s = 0.f;
    #pragma unroll
    for (int z = 0; z < 8; z++) s += part[(size_t)z * 131072 + idx];
    outp[idx] = s;
}

// ---------------- rn table: RMS-norm of (M[k] + bank_out[k]) ----------------
__global__ __launch_bounds__(256)
void rn_k(const float* __restrict__ Mw, const float* __restrict__ banko,
          const float* __restrict__ g, float* __restrict__ rn)
{
    int k = blockIdx.x, tid = threadIdx.x;
    __shared__ float red[256];
    float r0 = Mw[(size_t)k*512 + tid]       + banko[(size_t)k*512 + tid];
    float r1 = Mw[(size_t)k*512 + 256 + tid] + banko[(size_t)k*512 + 256 + tid];
    red[tid] = r0*r0 + r1*r1;
    __syncthreads();
    for (int s = 128; s > 0; s >>= 1) { if (tid < s) red[tid] += red[tid+s]; __syncthreads(); }
    float denom = sqrtf(red[0] * (1.0f/512.0f) + 1e-6f);
    rn[(size_t)k*512 + tid]       = r0 * (g[tid] / denom);
    rn[(size_t)k*512 + 256 + tid] = r1 * (g[256 + tid] / denom);
}

// ---------------- per-row argmax (first-index ties) + sticky 256-bit mask ----------------
__global__ __launch_bounds__(64)
void topmask_k(const float* __restrict__ logits, u64* __restrict__ masks,
               int* __restrict__ cArr)
{
    int row = blockIdx.x, l = threadIdx.x;
    const float* lg = logits + (size_t)row * 256;
    float v0 = lg[l], v1 = lg[64 + l], v2 = lg[128 + l], v3 = lg[192 + l];
    float bv = v0; int bp = l;
    if (v1 > bv) { bv = v1; bp = 64 + l; }
    if (v2 > bv) { bv = v2; bp = 128 + l; }
    if (v3 > bv) { bv = v3; bp = 192 + l; }
    #pragma unroll
    for (int off = 32; off; off >>= 1) {
        float ov = __shfl_xor(bv, off);
        int   op = __shfl_xor(bp, off);
        if (ov > bv || (ov == bv && op < bp)) { bv = ov; bp = op; }
    }
    float t0 = v0 + 0.1f, t1 = v1 + 0.1f, t2 = v2 + 0.1f, t3 = v3 + 0.1f;
    u64 w0 = __ballot((t0 > bv) || (t0 == bv && (l)       < bp));
    u64 w1 = __ballot((t1 > bv) || (t1 == bv && (64 + l)  < bp));
    u64 w2 = __ballot((t2 > bv) || (t2 == bv && (128 + l) < bp));
    u64 w3 = __ballot((t3 > bv) || (t3 == bv && (192 + l) < bp));
    if (l == 0) {
        masks[(size_t)row*4 + 0] = w0;
        masks[(size_t)row*4 + 1] = w1;
        masks[(size_t)row*4 + 2] = w2;
        masks[(size_t)row*4 + 3] = w3;
        cArr[row] = bp;
    }
}

// ---------------- flag rows with risky (small) decision margins ----------------
__global__ __launch_bounds__(64)
void flag_k(const float* __restrict__ logits, int* __restrict__ flags)
{
    int row = blockIdx.x, l = threadIdx.x;
    const float* lg = logits + (size_t)row * 256;
    float v0 = lg[l], v1 = lg[64 + l], v2 = lg[128 + l], v3 = lg[192 + l];
    float bv = v0; int bp = l;
    if (v1 > bv) { bv = v1; bp = 64 + l; }
    if (v2 > bv) { bv = v2; bp = 128 + l; }
    if (v3 > bv) { bv = v3; bp = 192 + l; }
    #pragma unroll
    for (int off = 32; off; off >>= 1) {
        float ov = __shfl_xor(bv, off);
        int   op = __shfl_xor(bp, off);
        if (ov > bv || (ov == bv && op < bp)) { bv = ov; bp = op; }
    }
    const float D = 1e-3f;
    bool r = false;
    r |= (v0 > bv - D) && ((l)       != bp);  r |= fabsf(v0 + 0.1f - bv) < D;
    r |= (v1 > bv - D) && ((64 + l)  != bp);  r |= fabsf(v1 + 0.1f - bv) < D;
    r |= (v2 > bv - D) && ((128 + l) != bp);  r |= fabsf(v2 + 0.1f - bv) < D;
    r |= (v3 > bv - D) && ((192 + l) != bp);  r |= fabsf(v3 + 0.1f - bv) < D;
    u64 any = __ballot(r);
    if (l == 0) flags[row] = (any != 0ULL) ? 1 : 0;
}

__global__ __launch_bounds__(256)
void compact_k(const int* __restrict__ flags, int* __restrict__ ridx, int* __restrict__ cnt)
{
    int row = blockIdx.x * 256 + threadIdx.x;
    if (row >= ROWS) return;
    if (flags[row]) {
        int p = atomicAdd(cnt, 1);
        if (p < FPAD) ridx[p] = row;
    }
}

__global__ __launch_bounds__(256)
void gatherx_k(const float* __restrict__ x, const int* __restrict__ ridx,
               const int* __restrict__ cnt, float* __restrict__ xg)
{
    int b = blockIdx.x;
    int n = *cnt; if (n > FPAD) n = FPAD;
    if (b >= n) return;
    int row = ridx[b];
    ((float4*)(xg + (size_t)b * 1024))[threadIdx.x] =
        ((const float4*)(x + (size_t)row * 1024))[threadIdx.x];
}

// ---------------- fixup reduce: h = relu(sum_z hPart + bias), cnt-gated ----------------
__global__ __launch_bounds__(256)
void redh_k(const float* __restrict__ part, const float* __restrict__ bias,
            const int* __restrict__ cnt, float* __restrict__ hg)
{
    int r = blockIdx.x;
    int n = *cnt; if (n > FPAD) n = FPAD;
    if (r >= n) return;
    int t = threadIdx.x;
    #pragma unroll
    for (int c0 = 0; c0 < HDIMD; c0 += 256) {
        int c = c0 + t;
        float s = part[(size_t)r * HDIMD + c];
        #pragma unroll
        for (int z = 1; z < KZ1; z++)
            s += part[(size_t)z * FPAD * HDIMD + (size_t)r * HDIMD + c];
        hg[(size_t)r * HDIMD + c] = fmaxf(s + bias[c], 0.f);
    }
}

// ---------------- fixup reduce: logits[ridx[b]] = sum_z lPart + bias ----------------
__global__ __launch_bounds__(256)
void redL_k(const float* __restrict__ part, const float* __restrict__ bias,
            const int* __restrict__ ridx, const int* __restrict__ cnt,
            float* __restrict__ logits)
{
    int b = blockIdx.x;
    int n = *cnt; if (n > FPAD) n = FPAD;
    if (b >= n) return;
    int t = threadIdx.x;
    float s = part[(size_t)b * KDIM + t];
    #pragma unroll
    for (int z = 1; z < KZ2; z++)
        s += part[(size_t)z * FPAD * KDIM + (size_t)b * KDIM + t];
    logits[(size_t)ridx[b] * KDIM + t] = s + bias[t];
}

// ========== parallel sticky-argmax scan: 3-phase chunked function composition ==========
__global__ __launch_bounds__(64)
void scanA_k(const u64* __restrict__ masks, const int* __restrict__ cArr,
             u32* __restrict__ chmap)   // [8*NCHK][64] u32 = 256 u8 states
{
    int blk = blockIdx.x;
    int l = threadIdx.x;
    int base = blk * 64;
    __shared__ u64 sm[64][4];
    __shared__ int sc[64];
    ulonglong2 m01 = *(const ulonglong2*)(masks + (size_t)(base + l) * 4);
    ulonglong2 m23 = *(const ulonglong2*)(masks + (size_t)(base + l) * 4 + 2);
    sm[l][0] = m01.x; sm[l][1] = m01.y; sm[l][2] = m23.x; sm[l][3] = m23.y;
    sc[l] = cArr[base + l];
    __syncthreads();

    int st[4];
    #pragma unroll
    for (int i = 0; i < 4; i++) st[i] = l * 4 + i;

    for (int j = 0; j < 64; ++j) {
        u64 w0 = sm[j][0], w1 = sm[j][1], w2 = sm[j][2], w3 = sm[j][3];
        int c = sc[j];
        #pragma unroll
        for (int i = 0; i < 4; i++) {
            int s = st[i];
            u64 wlo = (s & 64) ? w1 : w0;
            u64 whi = (s & 64) ? w3 : w2;
            u64 w   = (s & 128) ? whi : wlo;
            int stick = (int)((w >> (s & 63)) & 1ULL);
            st[i] = stick ? s : c;
        }
    }
    u32 outv = (u32)(st[0] & 255) | ((u32)(st[1] & 255) << 8)
             | ((u32)(st[2] & 255) << 16) | ((u32)(st[3] & 255) << 24);
    chmap[(size_t)blk * 64 + l] = outv;
}

__global__ __launch_bounds__(64)
void scanB_k(const u32* __restrict__ chmap, const float* __restrict__ prev_mode,
             int* __restrict__ entry)
{
    int b = blockIdx.x, l = threadIdx.x;
    __shared__ u8 lm[NCHK * 256];   // 8 KB
    const u32* src = chmap + (size_t)b * NCHK * 64;
    #pragma unroll
    for (int i = 0; i < NCHK; ++i) ((u32*)lm)[i * 64 + l] = src[i * 64 + l];

    float4 pm = ((const float4*)(prev_mode + (size_t)b * 256))[l];
    int my = -1;
    if (pm.x > 0.5f) my = l * 4 + 0;
    if (pm.y > 0.5f) my = l * 4 + 1;
    if (pm.z > 0.5f) my = l * 4 + 2;
    if (pm.w > 0.5f) my = l * 4 + 3;
    u64 bal = __ballot(my >= 0);
    int prev = 0;
    if (bal) {
        int s2 = __ffsll(bal) - 1;
        prev = __builtin_amdgcn_readlane(my, s2);
    }
    __syncthreads();
    if (l == 0) {
        int e = prev;
        for (int ci = 0; ci < NCHK; ++ci) {
            entry[b * NCHK + ci] = e;
            e = lm[ci * 256 + e];
        }
    }
}

__global__ __launch_bounds__(64)
void scanC_k(const u64* __restrict__ masks, const int* __restrict__ cArr,
             const int* __restrict__ entry, int* __restrict__ midx)
{
    int blk = blockIdx.x, l = threadIdx.x;
    int base = blk * 64;
    ulonglong2 c01 = *(const ulonglong2*)(masks + (size_t)(base + l) * 4);
    ulonglong2 c23 = *(const ulonglong2*)(masks + (size_t)(base + l) * 4 + 2);
    int cc = cArr[base + l];
    int prev = entry[blk];
    int myres = 0;
    for (int j = 0; j < 64; ++j) {
        u64 wlo = (prev & 64) ? c01.y : c01.x;
        u64 whi = (prev & 64) ? c23.y : c23.x;
        u64 w   = (prev & 128) ? whi : wlo;
        unsigned int lo32 = (unsigned int)__builtin_amdgcn_readlane((int)(unsigned int)w, j);
        unsigned int hi32 = (unsigned int)__builtin_amdgcn_readlane((int)(unsigned int)(w >> 32), j);
        int c = __builtin_amdgcn_readlane(cc, j);
        u64 ww = ((u64)hi32 << 32) | (u64)lo32;
        int stick = (int)((ww >> (prev & 63)) & 1ULL);
        prev = stick ? prev : c;
        myres = (l == j) ? prev : myres;
    }
    midx[base + l] = myres;
}

// ---------------- modes one-hot output ----------------
__global__ __launch_bounds__(64)
void modesw_k(const int* __restrict__ mode_idx, float* __restrict__ modes)
{
    int r = blockIdx.x, l = threadIdx.x;
    int k = mode_idx[r];
    int base = l * 4;
    float4 v = make_float4(base == k ? 1.f : 0.f, base+1 == k ? 1.f : 0.f,
                           base+2 == k ? 1.f : 0.f, base+3 == k ? 1.f : 0.f);
    ((float4*)(modes + (size_t)r * 256))[l] = v;
}

// ---------------- y gather from 256-entry table ----------------
__global__ __launch_bounds__(256)
void ygather_k(const int* __restrict__ mode_idx, const float* __restrict__ ytab,
               float* __restrict__ y)
{
    int r = blockIdx.x;
    int k = mode_idx[r];
    const float4* src = (const float4*)(ytab + (size_t)k * 1024);
    float4* dst = (float4*)(y + (size_t)r * 1024);
    dst[threadIdx.x] = src[threadIdx.x];
}

extern "C" void kernel_launch(void* const* d_in, const int* in_sizes, int n_in,
                              void* d_out, int out_size, void* d_ws, size_t ws_size,
                              hipStream_t stream)
{
    const float* x       = (const float*)d_in[0];
    const float* prevm   = (const float*)d_in[1];
    const float* Wtr_w   = (const float*)d_in[2];
    const float* Wtr_b   = (const float*)d_in[3];
    const float* Wms_w   = (const float*)d_in[4];
    const float* Wms_b   = (const float*)d_in[5];
    const float* Mw      = (const float*)d_in[6];
    const float* g       = (const float*)d_in[7];
    const float* Wrd_w   = (const float*)d_in[8];
    const float* Wrd_b   = (const float*)d_in[9];
    const float* bkeys   = (const float*)d_in[10];
    const float* bvals   = (const float*)d_in[11];
    const float* bused   = (const float*)d_in[12];

    float* y_out     = (float*)d_out;                       // [16384,1024]
    float* modes_out = y_out + (size_t)ROWS * DOUTD;        // [16384,256]

    char* w = (char*)d_ws;
    size_t o = 0;
    auto alloc = [&](size_t b) { size_t r = o; o = (o + b + 255) & ~(size_t)255; return r; };

    size_t oLog  = alloc((size_t)ROWS * 256 * 4);
    size_t oMask = alloc((size_t)ROWS * 32);
    size_t oCar  = alloc((size_t)ROWS * 4);
    size_t oMidx = alloc((size_t)ROWS * 4);
    size_t oInv  = alloc((size_t)BANKN * 4);
    size_t oSc   = alloc((size_t)256 * 4096 * 4);
    size_t oPB   = alloc((size_t)8 * 256 * 512 * 4);
    size_t oBo   = alloc((size_t)256 * 512 * 4);
    size_t oRn   = alloc((size_t)256 * 512 * 4);
    size_t oYt   = alloc((size_t)256 * 1024 * 4);
    size_t oW1m  = alloc((size_t)HDIMD * DIND * 2);   // Wtr^T main [2048 x 1024] f16
    size_t oW1r  = alloc((size_t)HDIMD * DIND * 2);   // Wtr^T res
    size_t oW2m  = alloc((size_t)KDIM * HDIMD * 2);   // Wms^T main [256 x 2048] f16
    size_t oW2r  = alloc((size_t)KDIM * HDIMD * 2);   // Wms^T res
    size_t oMwP  = alloc((size_t)KDIM * DMDIM * 4);   // Mw packed u32
    size_t oBkP  = alloc((size_t)BANKN * DMDIM * 4);  // bkeys packed [4096 x 512]
    size_t oAtP  = alloc((size_t)KDIM * BANKN * 4);   // attn packed [256 x 4096]
    size_t oBvP  = alloc((size_t)DMDIM * BANKN * 4);  // bvals^T packed [512 x 4096]
    size_t oRnP  = alloc((size_t)KDIM * DMDIM * 4);   // rn packed
    size_t oWrdP = alloc((size_t)DOUTD * DMDIM * 4);  // Wrd^T packed [1024 x 512]
    size_t oChm  = alloc((size_t)8 * NCHK * 256);     // chunk maps (u8 states)
    size_t oEnt  = alloc((size_t)8 * NCHK * 4);       // chunk entry states
    size_t oFlag = alloc((size_t)ROWS * 4);
    size_t oRidx = alloc((size_t)FPAD * 4);
    size_t oCnt  = alloc(256);
    size_t oXg   = alloc((size_t)FPAD * DIND * 4);            // 4 MB
    size_t oHP   = alloc((size_t)KZ1 * FPAD * HDIMD * 4);     // 16 MB
    size_t oHg   = alloc((size_t)FPAD * HDIMD * 4);           // 8 MB
    size_t oLP   = alloc((size_t)KZ2 * FPAD * KDIM * 4);      // 8 MB
    size_t persist = o;

    int CM = 256;
    const int cands[7] = {16384, 8192, 4096, 2048, 1024, 512, 256};
    for (int i = 0; i < 7; i++) {
        // per-row: xi 2048B + hi 4096B + part2 2*256*4=2048B = 8192B
        size_t need = persist + (size_t)cands[i] * 8192 + 1024;
        if (need <= ws_size) { CM = cands[i]; break; }
    }
    size_t oXi = alloc((size_t)CM * DIND * 2);
    size_t oHi = alloc((size_t)CM * HDIMD * 2);
    size_t oP2 = alloc((size_t)2 * CM * 256 * 4);

    float* logits = (float*)(w + oLog);
    u64*   masks  = (u64*)(w + oMask);
    int*   cArr   = (int*)(w + oCar);
    int*   midx   = (int*)(w + oMidx);
    float* invkn  = (float*)(w + oInv);
    float* scores = (float*)(w + oSc);
    float* partB  = (float*)(w + oPB);
    float* banko  = (float*)(w + oBo);
    float* rn     = (float*)(w + oRn);
    float* ytab   = (float*)(w + oYt);
    u16*   W1m    = (u16*)(w + oW1m);
    u16*   W1r    = (u16*)(w + oW1r);
    u16*   W2m    = (u16*)(w + oW2m);
    u16*   W2r    = (u16*)(w + oW2r);
    u32*   MwP    = (u32*)(w + oMwP);
    u32*   bkP    = (u32*)(w + oBkP);
    u32*   atP    = (u32*)(w + oAtP);
    u32*   bvP    = (u32*)(w + oBvP);
    u32*   rnP    = (u32*)(w + oRnP);
    u32*   WrdP   = (u32*)(w + oWrdP);
    u32*   chmap  = (u32*)(w + oChm);
    int*   entry  = (int*)(w + oEnt);
    int*   flags  = (int*)(w + oFlag);
    int*   ridx   = (int*)(w + oRidx);
    int*   cnt    = (int*)(w + oCnt);
    float* xg     = (float*)(w + oXg);
    float* hPart  = (float*)(w + oHP);
    float* hg     = (float*)(w + oHg);
    float* lPart  = (float*)(w + oLP);
    u16*   xi     = (u16*)(w + oXi);
    u16*   hi     = (u16*)(w + oHi);
    float* part2  = (float*)(w + oP2);

    // ---- mode table pipeline (split-split 3-MFMA, near-fp32) ----
    invkn_k<<<BANKN, 64, 0, stream>>>(bkeys, invkn);
    packrow_k<<<(KDIM * DMDIM / 4 + 255) / 256, 256, 0, stream>>>(Mw, MwP, KDIM * DMDIM / 4);
    packrow_k<<<(BANKN * DMDIM / 4 + 255) / 256, 256, 0, stream>>>(bkeys, bkP, BANKN * DMDIM / 4);
    tpack_k<<<dim3(DMDIM / 32, BANKN / 32), 256, 0, stream>>>(bvals, bvP, BANKN, DMDIM);
    tpack_k<<<dim3(DOUTD / 32, DMDIM / 32), 256, 0, stream>>>(Wrd_w, WrdP, DMDIM, DOUTD);
    // scores = Mw @ bkeys^T : [256 x 4096]
    gemm_sp3<false><<<dim3(BANKN / 128, KDIM / 128, 1), 256, 0, stream>>>(
        MwP, bkP, nullptr, scores, DMDIM, DMDIM);
    softmax_k<<<KDIM, 256, 0, stream>>>(Mw, invkn, bused, scores);
    packrow_k<<<(KDIM * BANKN / 4 + 255) / 256, 256, 0, stream>>>(scores, atP, KDIM * BANKN / 4);
    // bank partials = attn @ bvals : split-K=8 -> [8][256 x 512]
    gemm_sp3<false><<<dim3(DMDIM / 128, KDIM / 128, 8), 256, 0, stream>>>(
        atP, bvP, nullptr, partB, BANKN, BANKN / 8);
    redk_k<<<512, 256, 0, stream>>>(partB, banko);
    rn_k<<<KDIM, 256, 0, stream>>>(Mw, banko, g, rn);
    packrow_k<<<(KDIM * DMDIM / 4 + 255) / 256, 256, 0, stream>>>(rn, rnP, KDIM * DMDIM / 4);
    // ytab = rn @ Wrd + b : [256 x 1024]
    gemm_sp3<true><<<dim3(DOUTD / 128, KDIM / 128, 1), 256, 0, stream>>>(
        rnP, WrdP, Wrd_b, ytab, DMDIM, DMDIM);

    // ---- weight split+transpose (two f16 planes each) ----
    tsplit_k<<<dim3(HDIMD / 32, DIND / 32), 256, 0, stream>>>(Wtr_w, W1m, W1r, DIND, HDIMD);
    tsplit_k<<<dim3(KDIM / 32, HDIMD / 32), 256, 0, stream>>>(Wms_w, W2m, W2r, HDIMD, KDIM);

    // ---- front GEMMs via A-main/B-split f16 MFMA ----
    for (int ch0 = 0; ch0 < ROWS; ch0 += CM) {
        long n8 = (long)CM * DIND / 8;
        packx_k<<<(int)((n8 + 255) / 256), 256, 0, stream>>>(x + (size_t)ch0 * DIND, xi, n8);
        // h = relu(x@Wtr + b), f16 out
        gemm_mfma<true><<<dim3(HDIMD / 128, CM / 128, 1), 256, 0, stream>>>(
            (const f16*)xi, (const f16*)W1m, (const f16*)W1r, Wtr_b, hi, DIND, DIND);
        // logits partials = h@Wms (split-K = 2)
        gemm_mfma<false><<<dim3(KDIM / 128, CM / 128, 2), 256, 0, stream>>>(
            (const f16*)hi, (const f16*)W2m, (const f16*)W2r, nullptr, part2, HDIMD, HDIMD / 2);
        int total4 = CM * 256 / 4;
        reduce2_k<<<(total4 + 255) / 256, 256, 0, stream>>>(part2, Wms_b,
            logits + (size_t)ch0 * 256, total4, total4, 2);
    }

    // ---- fixup: recompute risky rows in exact fp32 (split-K gemm64, cnt-gated) ----
    flag_k<<<ROWS, 64, 0, stream>>>(logits, flags);
    hipMemsetAsync(cnt, 0, 4, stream);
    compact_k<<<ROWS / 256, 256, 0, stream>>>(flags, ridx, cnt);
    gatherx_k<<<FPAD, 256, 0, stream>>>(x, ridx, cnt, xg);
    // h partials: [kz][FPAD x 2048]
    gemm64<false, false, false><<<dim3(HDIMD / 64, FPAD / 64, KZ1), 256, 0, stream>>>(
        xg, Wtr_w, nullptr, hPart, FPAD, HDIMD, DIND, DIND / KZ1, cnt);
    redh_k<<<FPAD, 256, 0, stream>>>(hPart, Wtr_b, cnt, hg);
    // logit partials: [kz=8][FPAD x 256]
    gemm64<false, false, false><<<dim3(KDIM / 64, FPAD / 64, KZ2), 256, 0, stream>>>(
        hg, Wms_w, nullptr, lPart, FPAD, KDIM, HDIMD, HDIMD / KZ2, cnt);
    redL_k<<<FPAD, 256, 0, stream>>>(lPart, Wms_b, ridx, cnt, logits);

    // ---- mode selection: parallel chunked scan ----
    topmask_k<<<ROWS, 64, 0, stream>>>(logits, masks, cArr);
    scanA_k<<<8 * NCHK, 64, 0, stream>>>(masks, cArr, chmap);
    scanB_k<<<8, 64, 0, stream>>>(chmap, prevm, entry);
    scanC_k<<<8 * NCHK, 64, 0, stream>>>(masks, cArr, entry, midx);

    // ---- outputs ----
    modesw_k<<<ROWS, 64, 0, stream>>>(midx, modes_out);
    ygather_k<<<ROWS, 256, 0, stream>>>(midx, ytab, y_out);
}

// Round 6
// 620.653 us; speedup vs baseline: 1.0057x; 1.0057x over previous
//
#include <hip/hip_runtime.h>
#include <stdint.h>

#define ROWS   16384   // B*S
#define KDIM   256
#define DMDIM  512
#define DOUTD  1024
#define BANKN  4096
#define DIND   1024
#define HDIMD  2048
#define FPAD   1024    // max fixup rows
#define SCHUNK 64      // scan chunk length (steps)
#define NCHK   32      // 2048 / SCHUNK chunks per batch
#define KZ1    4       // fixup GEMM1 split-K
#define KZ2    8       // fixup GEMM2 split-K

typedef unsigned int u32;
typedef unsigned short u16;
typedef unsigned char u8;
typedef unsigned long long u64;
typedef _Float16 f16;
typedef _Float16 v8h __attribute__((ext_vector_type(8)));
typedef u16      v8u __attribute__((ext_vector_type(8)));
typedef u16      v4u __attribute__((ext_vector_type(4)));
typedef float    v4f __attribute__((ext_vector_type(4)));

// ---------- split helper (weights only): v = hi(f16) + lo(f16)*2^-11; lo stored pre-scaled by 2048 ----------
__device__ __forceinline__ u32 pack_split(float v) {
    _Float16 h = (_Float16)v;
    float r = (v - (float)h) * 2048.0f;     // exact scale; keeps lo in f16 normal range
    _Float16 l = (_Float16)r;
    u16 hs = __builtin_bit_cast(u16, h);
    u16 ls = __builtin_bit_cast(u16, l);
    return (u32)hs | ((u32)ls << 16);
}
__device__ __forceinline__ v4f mfma16(v8h a, v8h b, v4f c) {
    return __builtin_amdgcn_mfma_f32_16x16x32_f16(a, b, c, 0, 0, 0);
}
__device__ __forceinline__ void gl_lds16(const u32* g, u32* l) {
    __builtin_amdgcn_global_load_lds(g, l, 16, 0, 0);
}

// ---------------- split-f16 MFMA GEMM, A main-only, B = main+res planes ----------------
// A: [M x K] f16 (AF32=false) or f32 with in-kernel f16 conversion (AF32=true).
// Bm/Br: [N x K] f16 planes. 128x128 tile, BK=64, 4 waves.
// LDS layout: rows of 64 f16 (128B), 16B slots XOR-swizzled: byte = row*128 + 16*(slot ^ (row&7)).
// B staged via global_load_lds (linear LDS dest, inverse-swizzled per-lane global source).
// A (AF32): reg-staged float4 x2 -> cvt f16 -> ds_write_b128 at swizzled slot (same LDS image).
// OSPLIT: relu+bias -> f16 out. else: fp32 partial out at Cv + bz*M*N (split-K via gridDim.z).
template<bool OSPLIT, bool AF32>
__global__ __launch_bounds__(256, 2)
void gemm_mfma(const void* __restrict__ Av, const f16* __restrict__ Bm_,
               const f16* __restrict__ Br_, const float* __restrict__ bias,
               void* __restrict__ Cv, int K, int kLen)
{
    __shared__ f16 As[128 * 64];        // 16 KB
    __shared__ f16 Bs[2 * 128 * 64];    // 32 KB (main plane, then res plane)
    const int N = gridDim.x * 128;
    const int M = gridDim.y * 128;

    // XCD-aware remap: blocks sharing an A-panel stay on one XCD
    long gx = gridDim.x, gy = gridDim.y, gz = gridDim.z;
    long flat = ((long)blockIdx.z * gy + blockIdx.y) * gx + blockIdx.x;
    long nb = gx * gy * gz;
    long lid = (flat & 7) * (nb >> 3) + (flat >> 3);
    int bx = (int)(lid % gx);
    long t2 = lid / gx;
    int by = (int)(t2 % gy);
    int bz = (int)(t2 / gy);

    const int m0 = by * 128, n0 = bx * 128;
    const int kStart = bz * kLen;

    const int tid = threadIdx.x;
    const int lane = tid & 63, wv = tid >> 6;
    const int lx = lane & 15, q = lane >> 4;
    const int wm = (wv >> 1) * 64, wn = (wv & 1) * 64;

    // staging: chunk c = tid + r*256 (16B chunks). row = c>>3, slot j = c&7.
    // f16 path: content for slot j must be global k8 = j ^ (row&7) (inverse of read-side swizzle).
    // f32 path: read global linearly, ds_write to swizzled slot (same LDS image).
    const int rowb = tid >> 3;                       // + r*32 per r
    const int k8   = (tid & 7) ^ (rowb & 7);         // r*32 ≡ 0 (mod 8) -> same for all r
    const f16*  gA  = AF32 ? nullptr : (const f16*)Av + (size_t)(m0 + rowb) * K + kStart + k8 * 8;
    const float* gAf = AF32 ? (const float*)Av + (size_t)(m0 + rowb) * K + kStart + (tid & 7) * 8 : nullptr;
    const f16* gBm = Bm_ + (size_t)(n0 + rowb) * K + kStart + k8 * 8;
    const f16* gBr = Br_ + (size_t)(n0 + rowb) * K + kStart + k8 * 8;
    f16* lA  = As + (wv * 64) * 8;            // wave-uniform base; +r*2048 f16 per r
    f16* lBm = Bs + (wv * 64) * 8;
    f16* lBr = Bs + 8192 + (wv * 64) * 8;
    // A ds_write dest (f16 index), swizzled slot; +r*2048 per r
    const int aw = rowb * 64 + k8 * 8;

    // fragment LDS byte offsets: row*128 + ((s*64 + q*16) ^ ((row&7)<<4))
    int aOff[4][2], bOff[4][2];
    #pragma unroll
    for (int i = 0; i < 4; i++) {
        int ra = wm + i * 16 + lx;
        int rb = wn + i * 16 + lx;
        #pragma unroll
        for (int s = 0; s < 2; s++) {
            aOff[i][s] = ra * 128 + ((s * 64 + q * 16) ^ ((ra & 7) << 4));
            bOff[i][s] = rb * 128 + ((s * 64 + q * 16) ^ ((rb & 7) << 4));
        }
    }

    v4f acc1[4][4], acc2[4][4];
    #pragma unroll
    for (int i = 0; i < 4; i++)
        #pragma unroll
        for (int j = 0; j < 4; j++) { v4f z = {0.f, 0.f, 0.f, 0.f}; acc1[i][j] = z; acc2[i][j] = z; }

    for (int kt = 0; kt < kLen; kt += 64) {
        if (AF32) {
            float4 fa[4][2];
            #pragma unroll
            for (int r = 0; r < 4; r++) {
                fa[r][0] = *(const float4*)(gAf + (size_t)r * 32 * K);
                fa[r][1] = *(const float4*)(gAf + (size_t)r * 32 * K + 4);
            }
            gAf += 64;
            #pragma unroll
            for (int r = 0; r < 4; r++) {
                gl_lds16((const u32*)(gBm + (size_t)r * 32 * K), (u32*)(lBm + r * 2048));
                gl_lds16((const u32*)(gBr + (size_t)r * 32 * K), (u32*)(lBr + r * 2048));
            }
            #pragma unroll
            for (int r = 0; r < 4; r++) {
                v8u o;
                o[0] = __builtin_bit_cast(u16, (_Float16)fa[r][0].x);
                o[1] = __builtin_bit_cast(u16, (_Float16)fa[r][0].y);
                o[2] = __builtin_bit_cast(u16, (_Float16)fa[r][0].z);
                o[3] = __builtin_bit_cast(u16, (_Float16)fa[r][0].w);
                o[4] = __builtin_bit_cast(u16, (_Float16)fa[r][1].x);
                o[5] = __builtin_bit_cast(u16, (_Float16)fa[r][1].y);
                o[6] = __builtin_bit_cast(u16, (_Float16)fa[r][1].z);
                o[7] = __builtin_bit_cast(u16, (_Float16)fa[r][1].w);
                *(v8u*)(As + aw + r * 2048) = o;
            }
        } else {
            #pragma unroll
            for (int r = 0; r < 4; r++) {
                gl_lds16((const u32*)(gA  + (size_t)r * 32 * K), (u32*)(lA  + r * 2048));
                gl_lds16((const u32*)(gBm + (size_t)r * 32 * K), (u32*)(lBm + r * 2048));
                gl_lds16((const u32*)(gBr + (size_t)r * 32 * K), (u32*)(lBr + r * 2048));
            }
            gA += 64;
        }
        gBm += 64; gBr += 64;
        __syncthreads();

        #pragma unroll
        for (int s = 0; s < 2; s++) {
            v8h am[4], bm[4], br[4];
            #pragma unroll
            for (int i = 0; i < 4; i++) {
                am[i] = *(const v8h*)((const char*)As + aOff[i][s]);
                bm[i] = *(const v8h*)((const char*)Bs + bOff[i][s]);
                br[i] = *(const v8h*)((const char*)Bs + 16384 + bOff[i][s]);
            }
            #pragma unroll
            for (int mi = 0; mi < 4; mi++)
                #pragma unroll
                for (int ni = 0; ni < 4; ni++) {
                    acc1[mi][ni] = mfma16(am[mi], bm[ni], acc1[mi][ni]);
                    acc2[mi][ni] = mfma16(am[mi], br[ni], acc2[mi][ni]);
                }
        }
        __syncthreads();
    }

    const float RS = 1.0f / 2048.0f;
    #pragma unroll
    for (int mi = 0; mi < 4; mi++) {
        #pragma unroll
        for (int ni = 0; ni < 4; ni++) {
            int col = n0 + wn + ni * 16 + lx;
            #pragma unroll
            for (int r = 0; r < 4; r++) {
                int row = m0 + wm + mi * 16 + q * 4 + r;
                float v = acc1[mi][ni][r] + acc2[mi][ni][r] * RS;
                if (OSPLIT) {
                    v += bias[col];
                    v = fmaxf(v, 0.f);
                    ((u16*)Cv)[(size_t)row * N + col] = __builtin_bit_cast(u16, (_Float16)v);
                } else {
                    ((float*)Cv)[(size_t)bz * M * N + (size_t)row * N + col] = v;
                }
            }
        }
    }
}

// ---------------- transpose + split of weights: W[K x N] f32 -> main/res planes [N x K] f16 ----------------
__global__ __launch_bounds__(256)
void tsplit_k(const float* __restrict__ W, u16* __restrict__ Wm, u16* __restrict__ Wr,
              int K, int N)
{
    __shared__ u32 L[32][33];
    int k0 = blockIdx.y * 32, n0 = blockIdx.x * 32;
    int r = threadIdx.x >> 3, c4 = (threadIdx.x & 7) * 4;
    float4 v = *(const float4*)(W + (size_t)(k0 + r) * N + n0 + c4);
    L[r][c4 + 0] = pack_split(v.x);
    L[r][c4 + 1] = pack_split(v.y);
    L[r][c4 + 2] = pack_split(v.z);
    L[r][c4 + 3] = pack_split(v.w);
    __syncthreads();
    u32 o0 = L[c4 + 0][r], o1 = L[c4 + 1][r], o2 = L[c4 + 2][r], o3 = L[c4 + 3][r];
    v4u mo, ro;
    mo[0] = (u16)o0; mo[1] = (u16)o1; mo[2] = (u16)o2; mo[3] = (u16)o3;
    ro[0] = (u16)(o0 >> 16); ro[1] = (u16)(o1 >> 16); ro[2] = (u16)(o2 >> 16); ro[3] = (u16)(o3 >> 16);
    *(v4u*)(Wm + (size_t)(n0 + r) * K + k0 + c4) = mo;
    *(v4u*)(Wr + (size_t)(n0 + r) * K + k0 + c4) = ro;
}

// ---------------- reduce split-K partials + bias -> logits ----------------
__global__ __launch_bounds__(256)
void reduce2_k(const float* __restrict__ part, const float* __restrict__ bias,
               float* __restrict__ outp, int total4, int zStride4, int zc)
{
    int i = blockIdx.x * 256 + threadIdx.x;
    if (i >= total4) return;
    const float4* p = (const float4*)part;
    float4 s = p[i];
    for (int z = 1; z < zc; z++) {
        float4 t = p[(size_t)z * zStride4 + i];
        s.x += t.x; s.y += t.y; s.z += t.z; s.w += t.w;
    }
    float4 b = ((const float4*)bias)[i & 63];
    s.x += b.x; s.y += b.y; s.z += b.z; s.w += b.w;
    ((float4*)outp)[i] = s;
}

// ---------------- generic fp32 GEMM, 64x64 tile (table pipeline + fixup split-K) ----------------
template<bool BT, bool BIAS, bool RELU>
__global__ __launch_bounds__(256)
void gemm64(const float* __restrict__ A, const float* __restrict__ Bm,
            const float* __restrict__ bias, float* __restrict__ C,
            int M, int N, int K, int kLen, const int* __restrict__ mcount)
{
    if (mcount && (int)blockIdx.y * 64 >= *mcount) return;
    __shared__ float As[16][68];
    __shared__ float Bs[16][68];
    const int tid = threadIdx.x;
    const int tx = tid & 15, ty = tid >> 4;
    const int m0 = blockIdx.y * 64;
    const int n0 = blockIdx.x * 64;
    const int z  = blockIdx.z;
    const int kStart = z * kLen;
    float* Cz = C + (size_t)z * M * N;
    float acc[4][4];
    #pragma unroll
    for (int i = 0; i < 4; i++)
        #pragma unroll
        for (int j = 0; j < 4; j++) acc[i][j] = 0.f;

    for (int kt = kStart; kt < kStart + kLen; kt += 16) {
        {
            int m = tid >> 2, kq = tid & 3;
            float4 av = *(const float4*)(A + (size_t)(m0 + m) * K + kt + kq * 4);
            As[kq*4+0][m]=av.x; As[kq*4+1][m]=av.y; As[kq*4+2][m]=av.z; As[kq*4+3][m]=av.w;
        }
        if (BT) {
            int n = tid >> 2, kq = tid & 3;
            float4 bv = *(const float4*)(Bm + (size_t)(n0 + n) * K + kt + kq * 4);
            Bs[kq*4+0][n]=bv.x; Bs[kq*4+1][n]=bv.y; Bs[kq*4+2][n]=bv.z; Bs[kq*4+3][n]=bv.w;
        } else {
            int n4 = tid & 15, kk = tid >> 4;
            float4 bv = *(const float4*)(Bm + (size_t)(kt + kk) * N + n0 + n4 * 4);
            *(float4*)&Bs[kk][n4 * 4] = bv;
        }
        __syncthreads();
        #pragma unroll
        for (int k = 0; k < 16; k++) {
            float4 a0 = *(const float4*)&As[k][ty * 4];
            float4 b0 = *(const float4*)&Bs[k][tx * 4];
            float a[4] = {a0.x, a0.y, a0.z, a0.w};
            float b[4] = {b0.x, b0.y, b0.z, b0.w};
            #pragma unroll
            for (int i = 0; i < 4; i++)
                #pragma unroll
                for (int j = 0; j < 4; j++)
                    acc[i][j] = fmaf(a[i], b[j], acc[i][j]);
        }
        __syncthreads();
    }
    float4 bi = make_float4(0.f,0.f,0.f,0.f);
    if (BIAS) bi = *(const float4*)(bias + n0 + tx * 4);
    #pragma unroll
    for (int i = 0; i < 4; i++) {
        int m = m0 + ty * 4 + i;
        float o0 = acc[i][0]+bi.x, o1 = acc[i][1]+bi.y, o2 = acc[i][2]+bi.z, o3 = acc[i][3]+bi.w;
        if (RELU) { o0=fmaxf(o0,0.f); o1=fmaxf(o1,0.f); o2=fmaxf(o2,0.f); o3=fmaxf(o3,0.f); }
        *(float4*)(Cz + (size_t)m * N + n0 + tx * 4) = make_float4(o0, o1, o2, o3);
    }
}

// ---------------- 1/max(||bank_keys[n]||,1e-12) ----------------
__global__ __launch_bounds__(64)
void invkn_k(const float* __restrict__ keys, float* __restrict__ inv_kn)
{
    int n = blockIdx.x, l = threadIdx.x;
    const float4* r = (const float4*)(keys + (size_t)n * 512);
    float4 a = r[l], b = r[l + 64];
    float s = a.x*a.x + a.y*a.y + a.z*a.z + a.w*a.w
            + b.x*b.x + b.y*b.y + b.z*b.z + b.w*b.w;
    #pragma unroll
    for (int off = 32; off; off >>= 1) s += __shfl_xor(s, off);
    if (l == 0) inv_kn[n] = 1.0f / fmaxf(sqrtf(s), 1e-12f);
}

// ---------------- masked scaled softmax over 4096 slots, per k-row, in place ----------------
__global__ __launch_bounds__(256)
void softmax_k(const float* __restrict__ Mw, const float* __restrict__ inv_kn,
               const float* __restrict__ used, float* __restrict__ sc)
{
    const int k = blockIdx.x, tid = threadIdx.x;
    __shared__ float red[256];
    float m0 = Mw[(size_t)k*512 + tid];
    float m1 = Mw[(size_t)k*512 + 256 + tid];
    red[tid] = m0*m0 + m1*m1;
    __syncthreads();
    for (int s = 128; s > 0; s >>= 1) { if (tid < s) red[tid] += red[tid+s]; __syncthreads(); }
    float scale = 4.0f / fmaxf(sqrtf(red[0]), 1e-12f);
    __syncthreads();
    float vals[16];
    float mx = -3.0e38f;
    #pragma unroll
    for (int j = 0; j < 16; j++) {
        int n = j*256 + tid;
        float v = sc[(size_t)k*4096 + n] * scale * inv_kn[n];
        v = (used[n] > 0.5f) ? v : -1e30f;
        vals[j] = v; mx = fmaxf(mx, v);
    }
    red[tid] = mx; __syncthreads();
    for (int s = 128; s > 0; s >>= 1) { if (tid < s) red[tid] = fmaxf(red[tid], red[tid+s]); __syncthreads(); }
    mx = red[0]; __syncthreads();
    float sum = 0.f;
    #pragma unroll
    for (int j = 0; j < 16; j++) { float e = expf(vals[j] - mx); vals[j] = e; sum += e; }
    red[tid] = sum; __syncthreads();
    for (int s = 128; s > 0; s >>= 1) { if (tid < s) red[tid] += red[tid+s]; __syncthreads(); }
    float inv = 1.0f / red[0];
    #pragma unroll
    for (int j = 0; j < 16; j++) { int n = j*256 + tid; sc[(size_t)k*4096 + n] = vals[j] * inv; }
}

// ---------------- reduce bank split-K partials ----------------
__global__ __launch_bounds__(256)
void redk_k(const float* __restrict__ part, float* __restrict__ outp)
{
    int idx = blockIdx.x * 256 + threadIdx.x;   // 131072 total
    float s = 0.f;
    #pragma unroll
    for (int z = 0; z < 8; z++) s += part[(size_t)z * 131072 + idx];
    outp[idx] = s;
}

// ---------------- rn table: RMS-norm of (M[k] + bank_out[k]) ----------------
__global__ __launch_bounds__(256)
void rn_k(const float* __restrict__ Mw, const float* __restrict__ banko,
          const float* __restrict__ g, float* __restrict__ rn)
{
    int k = blockIdx.x, tid = threadIdx.x;
    __shared__ float red[256];
    float r0 = Mw[(size_t)k*512 + tid]       + banko[(size_t)k*512 + tid];
    float r1 = Mw[(size_t)k*512 + 256 + tid] + banko[(size_t)k*512 + 256 + tid];
    red[tid] = r0*r0 + r1*r1;
    __syncthreads();
    for (int s = 128; s > 0; s >>= 1) { if (tid < s) red[tid] += red[tid+s]; __syncthreads(); }
    float denom = sqrtf(red[0] * (1.0f/512.0f) + 1e-6f);
    rn[(size_t)k*512 + tid]       = r0 * (g[tid] / denom);
    rn[(size_t)k*512 + 256 + tid] = r1 * (g[256 + tid] / denom);
}

// ---------------- fused: per-row argmax + sticky mask + risky-margin flag ----------------
__global__ __launch_bounds__(64)
void topflag_k(const float* __restrict__ logits, u64* __restrict__ masks,
               int* __restrict__ cArr, int* __restrict__ flags)
{
    int row = blockIdx.x, l = threadIdx.x;
    const float* lg = logits + (size_t)row * 256;
    float v0 = lg[l], v1 = lg[64 + l], v2 = lg[128 + l], v3 = lg[192 + l];
    float bv = v0; int bp = l;
    if (v1 > bv) { bv = v1; bp = 64 + l; }
    if (v2 > bv) { bv = v2; bp = 128 + l; }
    if (v3 > bv) { bv = v3; bp = 192 + l; }
    #pragma unroll
    for (int off = 32; off; off >>= 1) {
        float ov = __shfl_xor(bv, off);
        int   op = __shfl_xor(bp, off);
        if (ov > bv || (ov == bv && op < bp)) { bv = ov; bp = op; }
    }
    float t0 = v0 + 0.1f, t1 = v1 + 0.1f, t2 = v2 + 0.1f, t3 = v3 + 0.1f;
    u64 w0 = __ballot((t0 > bv) || (t0 == bv && (l)       < bp));
    u64 w1 = __ballot((t1 > bv) || (t1 == bv && (64 + l)  < bp));
    u64 w2 = __ballot((t2 > bv) || (t2 == bv && (128 + l) < bp));
    u64 w3 = __ballot((t3 > bv) || (t3 == bv && (192 + l) < bp));
    const float D = 1e-3f;
    bool r = false;
    r |= (v0 > bv - D) && ((l)       != bp);  r |= fabsf(t0 - bv) < D;
    r |= (v1 > bv - D) && ((64 + l)  != bp);  r |= fabsf(t1 - bv) < D;
    r |= (v2 > bv - D) && ((128 + l) != bp);  r |= fabsf(t2 - bv) < D;
    r |= (v3 > bv - D) && ((192 + l) != bp);  r |= fabsf(t3 - bv) < D;
    u64 any = __ballot(r);
    if (l == 0) {
        masks[(size_t)row*4 + 0] = w0;
        masks[(size_t)row*4 + 1] = w1;
        masks[(size_t)row*4 + 2] = w2;
        masks[(size_t)row*4 + 3] = w3;
        cArr[row] = bp;
        flags[row] = (any != 0ULL) ? 1 : 0;
    }
}

__global__ __launch_bounds__(256)
void compact_k(const int* __restrict__ flags, int* __restrict__ ridx, int* __restrict__ cnt)
{
    int row = blockIdx.x * 256 + threadIdx.x;
    if (row >= ROWS) return;
    if (flags[row]) {
        int p = atomicAdd(cnt, 1);
        if (p < FPAD) ridx[p] = row;
    }
}

__global__ __launch_bounds__(256)
void gatherx_k(const float* __restrict__ x, const int* __restrict__ ridx,
               const int* __restrict__ cnt, float* __restrict__ xg)
{
    int b = blockIdx.x;
    int n = *cnt; if (n > FPAD) n = FPAD;
    if (b >= n) return;
    int row = ridx[b];
    ((float4*)(xg + (size_t)b * 1024))[threadIdx.x] =
        ((const float4*)(x + (size_t)row * 1024))[threadIdx.x];
}

// ---------------- fixup reduce: h = relu(sum_z hPart + bias), cnt-gated ----------------
__global__ __launch_bounds__(256)
void redh_k(const float* __restrict__ part, const float* __restrict__ bias,
            const int* __restrict__ cnt, float* __restrict__ hg)
{
    int r = blockIdx.x;
    int n = *cnt; if (n > FPAD) n = FPAD;
    if (r >= n) return;
    int t = threadIdx.x;
    #pragma unroll
    for (int c0 = 0; c0 < HDIMD; c0 += 256) {
        int c = c0 + t;
        float s = part[(size_t)r * HDIMD + c];
        #pragma unroll
        for (int z = 1; z < KZ1; z++)
            s += part[(size_t)z * FPAD * HDIMD + (size_t)r * HDIMD + c];
        hg[(size_t)r * HDIMD + c] = fmaxf(s + bias[c], 0.f);
    }
}

// ---------------- fixup reduce: logits[ridx[b]] = sum_z lPart + bias ----------------
__global__ __launch_bounds__(256)
void redL_k(const float* __restrict__ part, const float* __restrict__ bias,
            const int* __restrict__ ridx, const int* __restrict__ cnt,
            float* __restrict__ logits)
{
    int b = blockIdx.x;
    int n = *cnt; if (n > FPAD) n = FPAD;
    if (b >= n) return;
    int t = threadIdx.x;
    float s = part[(size_t)b * KDIM + t];
    #pragma unroll
    for (int z = 1; z < KZ2; z++)
        s += part[(size_t)z * FPAD * KDIM + (size_t)b * KDIM + t];
    logits[(size_t)ridx[b] * KDIM + t] = s + bias[t];
}

// ========== parallel sticky-argmax scan: 3-phase chunked function composition ==========
__global__ __launch_bounds__(64)
void scanA_k(const u64* __restrict__ masks, const int* __restrict__ cArr,
             u32* __restrict__ chmap)   // [8*NCHK][64] u32 = 256 u8 states
{
    int blk = blockIdx.x;
    int l = threadIdx.x;
    int base = blk * 64;
    __shared__ u64 sm[64][4];
    __shared__ int sc[64];
    ulonglong2 m01 = *(const ulonglong2*)(masks + (size_t)(base + l) * 4);
    ulonglong2 m23 = *(const ulonglong2*)(masks + (size_t)(base + l) * 4 + 2);
    sm[l][0] = m01.x; sm[l][1] = m01.y; sm[l][2] = m23.x; sm[l][3] = m23.y;
    sc[l] = cArr[base + l];
    __syncthreads();

    int st[4];
    #pragma unroll
    for (int i = 0; i < 4; i++) st[i] = l * 4 + i;

    for (int j = 0; j < 64; ++j) {
        u64 w0 = sm[j][0], w1 = sm[j][1], w2 = sm[j][2], w3 = sm[j][3];
        int c = sc[j];
        #pragma unroll
        for (int i = 0; i < 4; i++) {
            int s = st[i];
            u64 wlo = (s & 64) ? w1 : w0;
            u64 whi = (s & 64) ? w3 : w2;
            u64 w   = (s & 128) ? whi : wlo;
            int stick = (int)((w >> (s & 63)) & 1ULL);
            st[i] = stick ? s : c;
        }
    }
    u32 outv = (u32)(st[0] & 255) | ((u32)(st[1] & 255) << 8)
             | ((u32)(st[2] & 255) << 16) | ((u32)(st[3] & 255) << 24);
    chmap[(size_t)blk * 64 + l] = outv;
}

__global__ __launch_bounds__(64)
void scanB_k(const u32* __restrict__ chmap, const float* __restrict__ prev_mode,
             int* __restrict__ entry)
{
    int b = blockIdx.x, l = threadIdx.x;
    __shared__ u8 lm[NCHK * 256];   // 8 KB
    const u32* src = chmap + (size_t)b * NCHK * 64;
    #pragma unroll
    for (int i = 0; i < NCHK; ++i) ((u32*)lm)[i * 64 + l] = src[i * 64 + l];

    float4 pm = ((const float4*)(prev_mode + (size_t)b * 256))[l];
    int my = -1;
    if (pm.x > 0.5f) my = l * 4 + 0;
    if (pm.y > 0.5f) my = l * 4 + 1;
    if (pm.z > 0.5f) my = l * 4 + 2;
    if (pm.w > 0.5f) my = l * 4 + 3;
    u64 bal = __ballot(my >= 0);
    int prev = 0;
    if (bal) {
        int s2 = __ffsll(bal) - 1;
        prev = __builtin_amdgcn_readlane(my, s2);
    }
    __syncthreads();
    if (l == 0) {
        int e = prev;
        for (int ci = 0; ci < NCHK; ++ci) {
            entry[b * NCHK + ci] = e;
            e = lm[ci * 256 + e];
        }
    }
}

__global__ __launch_bounds__(64)
void scanC_k(const u64* __restrict__ masks, const int* __restrict__ cArr,
             const int* __restrict__ entry, int* __restrict__ midx)
{
    int blk = blockIdx.x, l = threadIdx.x;
    int base = blk * 64;
    ulonglong2 c01 = *(const ulonglong2*)(masks + (size_t)(base + l) * 4);
    ulonglong2 c23 = *(const ulonglong2*)(masks + (size_t)(base + l) * 4 + 2);
    int cc = cArr[base + l];
    int prev = entry[blk];
    int myres = 0;
    for (int j = 0; j < 64; ++j) {
        u64 wlo = (prev & 64) ? c01.y : c01.x;
        u64 whi = (prev & 64) ? c23.y : c23.x;
        u64 w   = (prev & 128) ? whi : wlo;
        unsigned int lo32 = (unsigned int)__builtin_amdgcn_readlane((int)(unsigned int)w, j);
        unsigned int hi32 = (unsigned int)__builtin_amdgcn_readlane((int)(unsigned int)(w >> 32), j);
        int c = __builtin_amdgcn_readlane(cc, j);
        u64 ww = ((u64)hi32 << 32) | (u64)lo32;
        int stick = (int)((ww >> (prev & 63)) & 1ULL);
        prev = stick ? prev : c;
        myres = (l == j) ? prev : myres;
    }
    midx[base + l] = myres;
}

// ---------------- fused outputs: y gather + modes one-hot ----------------
__global__ __launch_bounds__(256)
void yout_k(const int* __restrict__ mode_idx, const float* __restrict__ ytab,
            float* __restrict__ y, float* __restrict__ modes)
{
    int r = blockIdx.x, t = threadIdx.x;
    int k = mode_idx[r];
    ((float4*)(y + (size_t)r * 1024))[t] =
        ((const float4*)(ytab + (size_t)k * 1024))[t];
    if (t < 64) {
        int base = t * 4;
        float4 v = make_float4(base == k ? 1.f : 0.f, base+1 == k ? 1.f : 0.f,
                               base+2 == k ? 1.f : 0.f, base+3 == k ? 1.f : 0.f);
        ((float4*)(modes + (size_t)r * 256))[t] = v;
    }
}

extern "C" void kernel_launch(void* const* d_in, const int* in_sizes, int n_in,
                              void* d_out, int out_size, void* d_ws, size_t ws_size,
                              hipStream_t stream)
{
    const float* x       = (const float*)d_in[0];
    const float* prevm   = (const float*)d_in[1];
    const float* Wtr_w   = (const float*)d_in[2];
    const float* Wtr_b   = (const float*)d_in[3];
    const float* Wms_w   = (const float*)d_in[4];
    const float* Wms_b   = (const float*)d_in[5];
    const float* Mw      = (const float*)d_in[6];
    const float* g       = (const float*)d_in[7];
    const float* Wrd_w   = (const float*)d_in[8];
    const float* Wrd_b   = (const float*)d_in[9];
    const float* bkeys   = (const float*)d_in[10];
    const float* bvals   = (const float*)d_in[11];
    const float* bused   = (const float*)d_in[12];

    float* y_out     = (float*)d_out;                       // [16384,1024]
    float* modes_out = y_out + (size_t)ROWS * DOUTD;        // [16384,256]

    char* w = (char*)d_ws;
    size_t o = 0;
    auto alloc = [&](size_t b) { size_t r = o; o = (o + b + 255) & ~(size_t)255; return r; };

    size_t oLog  = alloc((size_t)ROWS * 256 * 4);
    size_t oMask = alloc((size_t)ROWS * 32);
    size_t oCar  = alloc((size_t)ROWS * 4);
    size_t oMidx = alloc((size_t)ROWS * 4);
    size_t oInv  = alloc((size_t)BANKN * 4);
    size_t oSc   = alloc((size_t)256 * 4096 * 4);
    size_t oPB   = alloc((size_t)8 * 256 * 512 * 4);
    size_t oBo   = alloc((size_t)256 * 512 * 4);
    size_t oRn   = alloc((size_t)256 * 512 * 4);
    size_t oYt   = alloc((size_t)256 * 1024 * 4);
    size_t oW1m  = alloc((size_t)HDIMD * DIND * 2);   // Wtr^T main [2048 x 1024] f16
    size_t oW1r  = alloc((size_t)HDIMD * DIND * 2);   // Wtr^T res
    size_t oW2m  = alloc((size_t)KDIM * HDIMD * 2);   // Wms^T main [256 x 2048] f16
    size_t oW2r  = alloc((size_t)KDIM * HDIMD * 2);   // Wms^T res
    size_t oChm  = alloc((size_t)8 * NCHK * 256);     // chunk maps (u8 states)
    size_t oEnt  = alloc((size_t)8 * NCHK * 4);       // chunk entry states
    size_t oFlag = alloc((size_t)ROWS * 4);
    size_t oRidx = alloc((size_t)FPAD * 4);
    size_t oCnt  = alloc(256);
    size_t oXg   = alloc((size_t)FPAD * DIND * 4);            // 4 MB
    size_t oHP   = alloc((size_t)KZ1 * FPAD * HDIMD * 4);     // 32 MB
    size_t oHg   = alloc((size_t)FPAD * HDIMD * 4);           // 8 MB
    size_t oLP   = alloc((size_t)KZ2 * FPAD * KDIM * 4);      // 8 MB
    size_t persist = o;

    int CM = 256;
    const int cands[7] = {16384, 8192, 4096, 2048, 1024, 512, 256};
    for (int i = 0; i < 7; i++) {
        // per-row: hi 4096B + part2 4*256*4=4096B = 8192B
        size_t need = persist + (size_t)cands[i] * 8192 + 1024;
        if (need <= ws_size) { CM = cands[i]; break; }
    }
    size_t oHi = alloc((size_t)CM * HDIMD * 2);
    size_t oP2 = alloc((size_t)4 * CM * 256 * 4);

    float* logits = (float*)(w + oLog);
    u64*   masks  = (u64*)(w + oMask);
    int*   cArr   = (int*)(w + oCar);
    int*   midx   = (int*)(w + oMidx);
    float* invkn  = (float*)(w + oInv);
    float* scores = (float*)(w + oSc);
    float* partB  = (float*)(w + oPB);
    float* banko  = (float*)(w + oBo);
    float* rn     = (float*)(w + oRn);
    float* ytab   = (float*)(w + oYt);
    u16*   W1m    = (u16*)(w + oW1m);
    u16*   W1r    = (u16*)(w + oW1r);
    u16*   W2m    = (u16*)(w + oW2m);
    u16*   W2r    = (u16*)(w + oW2r);
    u32*   chmap  = (u32*)(w + oChm);
    int*   entry  = (int*)(w + oEnt);
    int*   flags  = (int*)(w + oFlag);
    int*   ridx   = (int*)(w + oRidx);
    int*   cnt    = (int*)(w + oCnt);
    float* xg     = (float*)(w + oXg);
    float* hPart  = (float*)(w + oHP);
    float* hg     = (float*)(w + oHg);
    float* lPart  = (float*)(w + oLP);
    u16*   hi     = (u16*)(w + oHi);
    float* part2  = (float*)(w + oP2);

    // ---- mode table pipeline (fp32, independent of front GEMMs) ----
    invkn_k<<<BANKN, 64, 0, stream>>>(bkeys, invkn);
    gemm64<true, false, false><<<dim3(64, 4, 1), 256, 0, stream>>>(Mw, bkeys, nullptr, scores,
                                                                   256, 4096, 512, 512, nullptr);
    softmax_k<<<KDIM, 256, 0, stream>>>(Mw, invkn, bused, scores);
    gemm64<false, false, false><<<dim3(8, 4, 8), 256, 0, stream>>>(scores, bvals, nullptr, partB,
                                                                   256, 512, 4096, 512, nullptr);
    redk_k<<<512, 256, 0, stream>>>(partB, banko);
    rn_k<<<KDIM, 256, 0, stream>>>(Mw, banko, g, rn);
    gemm64<false, true, false><<<dim3(16, 4, 1), 256, 0, stream>>>(rn, Wrd_w, Wrd_b, ytab,
                                                                   256, 1024, 512, 512, nullptr);

    // ---- weight split+transpose (two f16 planes each) ----
    tsplit_k<<<dim3(HDIMD / 32, DIND / 32), 256, 0, stream>>>(Wtr_w, W1m, W1r, DIND, HDIMD);
    tsplit_k<<<dim3(KDIM / 32, HDIMD / 32), 256, 0, stream>>>(Wms_w, W2m, W2r, HDIMD, KDIM);

    // ---- front GEMMs via A-main/B-split f16 MFMA (x converted in-kernel) ----
    for (int ch0 = 0; ch0 < ROWS; ch0 += CM) {
        // h = relu(x@Wtr + b), f16 out; A read directly from f32 x
        gemm_mfma<true, true><<<dim3(HDIMD / 128, CM / 128, 1), 256, 0, stream>>>(
            (const void*)(x + (size_t)ch0 * DIND), (const f16*)W1m, (const f16*)W1r,
            Wtr_b, hi, DIND, DIND);
        // logits partials = h@Wms (split-K = 4)
        gemm_mfma<false, false><<<dim3(KDIM / 128, CM / 128, 4), 256, 0, stream>>>(
            (const void*)hi, (const f16*)W2m, (const f16*)W2r, nullptr, part2, HDIMD, HDIMD / 4);
        int total4 = CM * 256 / 4;
        reduce2_k<<<(total4 + 255) / 256, 256, 0, stream>>>(part2, Wms_b,
            logits + (size_t)ch0 * 256, total4, total4, 4);
    }

    // ---- fixup: recompute risky rows in exact fp32 (split-K gemm64, cnt-gated) ----
    topflag_k<<<ROWS, 64, 0, stream>>>(logits, masks, cArr, flags);
    hipMemsetAsync(cnt, 0, 4, stream);
    compact_k<<<ROWS / 256, 256, 0, stream>>>(flags, ridx, cnt);
    gatherx_k<<<FPAD, 256, 0, stream>>>(x, ridx, cnt, xg);
    // h partials: [kz=4][FPAD x 2048]
    gemm64<false, false, false><<<dim3(HDIMD / 64, FPAD / 64, KZ1), 256, 0, stream>>>(
        xg, Wtr_w, nullptr, hPart, FPAD, HDIMD, DIND, DIND / KZ1, cnt);
    redh_k<<<FPAD, 256, 0, stream>>>(hPart, Wtr_b, cnt, hg);
    // logit partials: [kz=8][FPAD x 256]
    gemm64<false, false, false><<<dim3(KDIM / 64, FPAD / 64, KZ2), 256, 0, stream>>>(
        hg, Wms_w, nullptr, lPart, FPAD, KDIM, HDIMD, HDIMD / KZ2, cnt);
    redL_k<<<FPAD, 256, 0, stream>>>(lPart, Wms_b, ridx, cnt, logits);
    // re-run topmask on fixed rows' logits (masks/cArr must reflect fixups):
    topflag_k<<<ROWS, 64, 0, stream>>>(logits, masks, cArr, flags);

    // ---- mode selection: parallel chunked scan ----
    scanA_k<<<8 * NCHK, 64, 0, stream>>>(masks, cArr, chmap);
    scanB_k<<<8, 64, 0, stream>>>(chmap, prevm, entry);
    scanC_k<<<8 * NCHK, 64, 0, stream>>>(masks, cArr, entry, midx);

    // ---- outputs ----
    yout_k<<<ROWS, 256, 0, stream>>>(midx, ytab, y_out, modes_out);
}

// Round 7
// 579.521 us; speedup vs baseline: 1.0770x; 1.0710x over previous
//
#include <hip/hip_runtime.h>
#include <stdint.h>

#define ROWS   16384   // B*S
#define KDIM   256
#define DMDIM  512
#define DOUTD  1024
#define BANKN  4096
#define DIND   1024
#define HDIMD  2048
#define FPAD   1024    // max fixup rows
#define SCHUNK 64      // scan chunk length (steps)
#define NCHK   32      // 2048 / SCHUNK chunks per batch
#define KZ1    4       // fixup GEMM1 split-K
#define KZ2    8       // fixup GEMM2 split-K

typedef unsigned int u32;
typedef unsigned short u16;
typedef unsigned char u8;
typedef unsigned long long u64;
typedef _Float16 f16;
typedef _Float16 v8h __attribute__((ext_vector_type(8)));
typedef u16      v8u __attribute__((ext_vector_type(8)));
typedef u16      v4u __attribute__((ext_vector_type(4)));
typedef float    v4f __attribute__((ext_vector_type(4)));

// ---------- split helper (weights only): v = hi(f16) + lo(f16)*2^-11; lo stored pre-scaled by 2048 ----------
__device__ __forceinline__ u32 pack_split(float v) {
    _Float16 h = (_Float16)v;
    float r = (v - (float)h) * 2048.0f;     // exact scale; keeps lo in f16 normal range
    _Float16 l = (_Float16)r;
    u16 hs = __builtin_bit_cast(u16, h);
    u16 ls = __builtin_bit_cast(u16, l);
    return (u32)hs | ((u32)ls << 16);
}
__device__ __forceinline__ v4f mfma16(v8h a, v8h b, v4f c) {
    return __builtin_amdgcn_mfma_f32_16x16x32_f16(a, b, c, 0, 0, 0);
}
__device__ __forceinline__ void gl_lds16(const u32* g, u32* l) {
    __builtin_amdgcn_global_load_lds(g, l, 16, 0, 0);
}

// ---------------- split-f16 MFMA GEMM, A main-only, B = main+res planes (round-4 proven) ----------------
// A: [M x K] f16. Bm/Br: [N x K] f16 planes. 128x128 tile, BK=64, 4 waves.
// LDS layout: rows of 64 f16 (128B), 16B slots XOR-swizzled: byte = row*128 + 16*(slot ^ (row&7)).
// Staged via global_load_lds (linear LDS dest) with inverse-swizzled per-lane global source.
// OSPLIT: relu+bias -> f16 out. else: fp32 partial out at Cv + bz*M*N (split-K via gridDim.z).
template<bool OSPLIT>
__global__ __launch_bounds__(256, 2)
void gemm_mfma(const f16* __restrict__ A, const f16* __restrict__ Bm_,
               const f16* __restrict__ Br_, const float* __restrict__ bias,
               void* __restrict__ Cv, int K, int kLen)
{
    __shared__ f16 As[128 * 64];        // 16 KB
    __shared__ f16 Bs[2 * 128 * 64];    // 32 KB (main plane, then res plane)
    const int N = gridDim.x * 128;
    const int M = gridDim.y * 128;

    // XCD-aware remap: blocks sharing an A-panel stay on one XCD
    long gx = gridDim.x, gy = gridDim.y, gz = gridDim.z;
    long flat = ((long)blockIdx.z * gy + blockIdx.y) * gx + blockIdx.x;
    long nb = gx * gy * gz;
    long lid = (flat & 7) * (nb >> 3) + (flat >> 3);
    int bx = (int)(lid % gx);
    long t2 = lid / gx;
    int by = (int)(t2 % gy);
    int bz = (int)(t2 / gy);

    const int m0 = by * 128, n0 = bx * 128;
    const int kStart = bz * kLen;

    const int tid = threadIdx.x;
    const int lane = tid & 63, wv = tid >> 6;
    const int lx = lane & 15, q = lane >> 4;
    const int wm = (wv >> 1) * 64, wn = (wv & 1) * 64;

    // staging: chunk c = tid + r*256 (16B chunks). row = c>>3, slot j = c&7.
    // content for slot j must be global k8 = j ^ (row&7)  (inverse of read-side XOR swizzle).
    const int rowb = tid >> 3;                       // + r*32 per r
    const int k8   = (tid & 7) ^ (rowb & 7);         // r*32 ≡ 0 (mod 8) -> same for all r
    const f16* gA  = A   + (size_t)(m0 + rowb) * K + kStart + k8 * 8;
    const f16* gBm = Bm_ + (size_t)(n0 + rowb) * K + kStart + k8 * 8;
    const f16* gBr = Br_ + (size_t)(n0 + rowb) * K + kStart + k8 * 8;
    f16* lA  = As + (wv * 64) * 8;            // wave-uniform base; +r*2048 f16 per r
    f16* lBm = Bs + (wv * 64) * 8;
    f16* lBr = Bs + 8192 + (wv * 64) * 8;

    // fragment LDS byte offsets: row*128 + ((s*64 + q*16) ^ ((row&7)<<4))
    int aOff[4][2], bOff[4][2];
    #pragma unroll
    for (int i = 0; i < 4; i++) {
        int ra = wm + i * 16 + lx;
        int rb = wn + i * 16 + lx;
        #pragma unroll
        for (int s = 0; s < 2; s++) {
            aOff[i][s] = ra * 128 + ((s * 64 + q * 16) ^ ((ra & 7) << 4));
            bOff[i][s] = rb * 128 + ((s * 64 + q * 16) ^ ((rb & 7) << 4));
        }
    }

    v4f acc1[4][4], acc2[4][4];
    #pragma unroll
    for (int i = 0; i < 4; i++)
        #pragma unroll
        for (int j = 0; j < 4; j++) { v4f z = {0.f, 0.f, 0.f, 0.f}; acc1[i][j] = z; acc2[i][j] = z; }

    for (int kt = 0; kt < kLen; kt += 64) {
        #pragma unroll
        for (int r = 0; r < 4; r++) {
            gl_lds16((const u32*)(gA  + (size_t)r * 32 * K), (u32*)(lA  + r * 2048));
            gl_lds16((const u32*)(gBm + (size_t)r * 32 * K), (u32*)(lBm + r * 2048));
            gl_lds16((const u32*)(gBr + (size_t)r * 32 * K), (u32*)(lBr + r * 2048));
        }
        gA += 64; gBm += 64; gBr += 64;
        __syncthreads();

        #pragma unroll
        for (int s = 0; s < 2; s++) {
            v8h am[4], bm[4], br[4];
            #pragma unroll
            for (int i = 0; i < 4; i++) {
                am[i] = *(const v8h*)((const char*)As + aOff[i][s]);
                bm[i] = *(const v8h*)((const char*)Bs + bOff[i][s]);
                br[i] = *(const v8h*)((const char*)Bs + 16384 + bOff[i][s]);
            }
            #pragma unroll
            for (int mi = 0; mi < 4; mi++)
                #pragma unroll
                for (int ni = 0; ni < 4; ni++) {
                    acc1[mi][ni] = mfma16(am[mi], bm[ni], acc1[mi][ni]);
                    acc2[mi][ni] = mfma16(am[mi], br[ni], acc2[mi][ni]);
                }
        }
        __syncthreads();
    }

    const float RS = 1.0f / 2048.0f;
    #pragma unroll
    for (int mi = 0; mi < 4; mi++) {
        #pragma unroll
        for (int ni = 0; ni < 4; ni++) {
            int col = n0 + wn + ni * 16 + lx;
            #pragma unroll
            for (int r = 0; r < 4; r++) {
                int row = m0 + wm + mi * 16 + q * 4 + r;
                float v = acc1[mi][ni][r] + acc2[mi][ni][r] * RS;
                if (OSPLIT) {
                    v += bias[col];
                    v = fmaxf(v, 0.f);
                    ((u16*)Cv)[(size_t)row * N + col] = __builtin_bit_cast(u16, (_Float16)v);
                } else {
                    ((float*)Cv)[(size_t)bz * M * N + (size_t)row * N + col] = v;
                }
            }
        }
    }
}

// ---------------- elementwise f16 pack of x (main plane only) ----------------
__global__ __launch_bounds__(256)
void packx_k(const float* __restrict__ x, u16* __restrict__ xo, long n8)
{
    long i = (long)blockIdx.x * 256 + threadIdx.x;
    if (i >= n8) return;
    const float4* xp = (const float4*)x;
    float4 a = xp[2 * i], b = xp[2 * i + 1];
    v8u o;
    o[0] = __builtin_bit_cast(u16, (_Float16)a.x);
    o[1] = __builtin_bit_cast(u16, (_Float16)a.y);
    o[2] = __builtin_bit_cast(u16, (_Float16)a.z);
    o[3] = __builtin_bit_cast(u16, (_Float16)a.w);
    o[4] = __builtin_bit_cast(u16, (_Float16)b.x);
    o[5] = __builtin_bit_cast(u16, (_Float16)b.y);
    o[6] = __builtin_bit_cast(u16, (_Float16)b.z);
    o[7] = __builtin_bit_cast(u16, (_Float16)b.w);
    *(v8u*)(xo + i * 8) = o;
}

// ---------------- transpose + split of weights: W[K x N] f32 -> main/res planes [N x K] f16 ----------------
__global__ __launch_bounds__(256)
void tsplit_k(const float* __restrict__ W, u16* __restrict__ Wm, u16* __restrict__ Wr,
              int K, int N)
{
    __shared__ u32 L[32][33];
    int k0 = blockIdx.y * 32, n0 = blockIdx.x * 32;
    int r = threadIdx.x >> 3, c4 = (threadIdx.x & 7) * 4;
    float4 v = *(const float4*)(W + (size_t)(k0 + r) * N + n0 + c4);
    L[r][c4 + 0] = pack_split(v.x);
    L[r][c4 + 1] = pack_split(v.y);
    L[r][c4 + 2] = pack_split(v.z);
    L[r][c4 + 3] = pack_split(v.w);
    __syncthreads();
    u32 o0 = L[c4 + 0][r], o1 = L[c4 + 1][r], o2 = L[c4 + 2][r], o3 = L[c4 + 3][r];
    v4u mo, ro;
    mo[0] = (u16)o0; mo[1] = (u16)o1; mo[2] = (u16)o2; mo[3] = (u16)o3;
    ro[0] = (u16)(o0 >> 16); ro[1] = (u16)(o1 >> 16); ro[2] = (u16)(o2 >> 16); ro[3] = (u16)(o3 >> 16);
    *(v4u*)(Wm + (size_t)(n0 + r) * K + k0 + c4) = mo;
    *(v4u*)(Wr + (size_t)(n0 + r) * K + k0 + c4) = ro;
}

// ---------------- reduce split-K partials + bias -> logits ----------------
__global__ __launch_bounds__(256)
void reduce2_k(const float* __restrict__ part, const float* __restrict__ bias,
               float* __restrict__ outp, int total4, int zStride4, int zc)
{
    int i = blockIdx.x * 256 + threadIdx.x;
    if (i >= total4) return;
    const float4* p = (const float4*)part;
    float4 s = p[i];
    for (int z = 1; z < zc; z++) {
        float4 t = p[(size_t)z * zStride4 + i];
        s.x += t.x; s.y += t.y; s.z += t.z; s.w += t.w;
    }
    float4 b = ((const float4*)bias)[i & 63];
    s.x += b.x; s.y += b.y; s.z += b.z; s.w += b.w;
    ((float4*)outp)[i] = s;
}

// ---------------- generic fp32 GEMM, 64x64 tile (table pipeline + fixup split-K) ----------------
template<bool BT, bool BIAS, bool RELU>
__global__ __launch_bounds__(256)
void gemm64(const float* __restrict__ A, const float* __restrict__ Bm,
            const float* __restrict__ bias, float* __restrict__ C,
            int M, int N, int K, int kLen, const int* __restrict__ mcount)
{
    if (mcount && (int)blockIdx.y * 64 >= *mcount) return;
    __shared__ float As[16][68];
    __shared__ float Bs[16][68];
    const int tid = threadIdx.x;
    const int tx = tid & 15, ty = tid >> 4;
    const int m0 = blockIdx.y * 64;
    const int n0 = blockIdx.x * 64;
    const int z  = blockIdx.z;
    const int kStart = z * kLen;
    float* Cz = C + (size_t)z * M * N;
    float acc[4][4];
    #pragma unroll
    for (int i = 0; i < 4; i++)
        #pragma unroll
        for (int j = 0; j < 4; j++) acc[i][j] = 0.f;

    for (int kt = kStart; kt < kStart + kLen; kt += 16) {
        {
            int m = tid >> 2, kq = tid & 3;
            float4 av = *(const float4*)(A + (size_t)(m0 + m) * K + kt + kq * 4);
            As[kq*4+0][m]=av.x; As[kq*4+1][m]=av.y; As[kq*4+2][m]=av.z; As[kq*4+3][m]=av.w;
        }
        if (BT) {
            int n = tid >> 2, kq = tid & 3;
            float4 bv = *(const float4*)(Bm + (size_t)(n0 + n) * K + kt + kq * 4);
            Bs[kq*4+0][n]=bv.x; Bs[kq*4+1][n]=bv.y; Bs[kq*4+2][n]=bv.z; Bs[kq*4+3][n]=bv.w;
        } else {
            int n4 = tid & 15, kk = tid >> 4;
            float4 bv = *(const float4*)(Bm + (size_t)(kt + kk) * N + n0 + n4 * 4);
            *(float4*)&Bs[kk][n4 * 4] = bv;
        }
        __syncthreads();
        #pragma unroll
        for (int k = 0; k < 16; k++) {
            float4 a0 = *(const float4*)&As[k][ty * 4];
            float4 b0 = *(const float4*)&Bs[k][tx * 4];
            float a[4] = {a0.x, a0.y, a0.z, a0.w};
            float b[4] = {b0.x, b0.y, b0.z, b0.w};
            #pragma unroll
            for (int i = 0; i < 4; i++)
                #pragma unroll
                for (int j = 0; j < 4; j++)
                    acc[i][j] = fmaf(a[i], b[j], acc[i][j]);
        }
        __syncthreads();
    }
    float4 bi = make_float4(0.f,0.f,0.f,0.f);
    if (BIAS) bi = *(const float4*)(bias + n0 + tx * 4);
    #pragma unroll
    for (int i = 0; i < 4; i++) {
        int m = m0 + ty * 4 + i;
        float o0 = acc[i][0]+bi.x, o1 = acc[i][1]+bi.y, o2 = acc[i][2]+bi.z, o3 = acc[i][3]+bi.w;
        if (RELU) { o0=fmaxf(o0,0.f); o1=fmaxf(o1,0.f); o2=fmaxf(o2,0.f); o3=fmaxf(o3,0.f); }
        *(float4*)(Cz + (size_t)m * N + n0 + tx * 4) = make_float4(o0, o1, o2, o3);
    }
}

// ---------------- 1/max(||bank_keys[n]||,1e-12) ----------------
__global__ __launch_bounds__(64)
void invkn_k(const float* __restrict__ keys, float* __restrict__ inv_kn)
{
    int n = blockIdx.x, l = threadIdx.x;
    const float4* r = (const float4*)(keys + (size_t)n * 512);
    float4 a = r[l], b = r[l + 64];
    float s = a.x*a.x + a.y*a.y + a.z*a.z + a.w*a.w
            + b.x*b.x + b.y*b.y + b.z*b.z + b.w*b.w;
    #pragma unroll
    for (int off = 32; off; off >>= 1) s += __shfl_xor(s, off);
    if (l == 0) inv_kn[n] = 1.0f / fmaxf(sqrtf(s), 1e-12f);
}

// ---------------- masked scaled softmax over 4096 slots, per k-row, in place ----------------
__global__ __launch_bounds__(256)
void softmax_k(const float* __restrict__ Mw, const float* __restrict__ inv_kn,
               const float* __restrict__ used, float* __restrict__ sc)
{
    const int k = blockIdx.x, tid = threadIdx.x;
    __shared__ float red[256];
    float m0 = Mw[(size_t)k*512 + tid];
    float m1 = Mw[(size_t)k*512 + 256 + tid];
    red[tid] = m0*m0 + m1*m1;
    __syncthreads();
    for (int s = 128; s > 0; s >>= 1) { if (tid < s) red[tid] += red[tid+s]; __syncthreads(); }
    float scale = 4.0f / fmaxf(sqrtf(red[0]), 1e-12f);
    __syncthreads();
    float vals[16];
    float mx = -3.0e38f;
    #pragma unroll
    for (int j = 0; j < 16; j++) {
        int n = j*256 + tid;
        float v = sc[(size_t)k*4096 + n] * scale * inv_kn[n];
        v = (used[n] > 0.5f) ? v : -1e30f;
        vals[j] = v; mx = fmaxf(mx, v);
    }
    red[tid] = mx; __syncthreads();
    for (int s = 128; s > 0; s >>= 1) { if (tid < s) red[tid] = fmaxf(red[tid], red[tid+s]); __syncthreads(); }
    mx = red[0]; __syncthreads();
    float sum = 0.f;
    #pragma unroll
    for (int j = 0; j < 16; j++) { float e = expf(vals[j] - mx); vals[j] = e; sum += e; }
    red[tid] = sum; __syncthreads();
    for (int s = 128; s > 0; s >>= 1) { if (tid < s) red[tid] += red[tid+s]; __syncthreads(); }
    float inv = 1.0f / red[0];
    #pragma unroll
    for (int j = 0; j < 16; j++) { int n = j*256 + tid; sc[(size_t)k*4096 + n] = vals[j] * inv; }
}

// ---------------- reduce bank split-K partials ----------------
__global__ __launch_bounds__(256)
void redk_k(const float* __restrict__ part, float* __restrict__ outp)
{
    int idx = blockIdx.x * 256 + threadIdx.x;   // 131072 total
    float s = 0.f;
    #pragma unroll
    for (int z = 0; z < 8; z++) s += part[(size_t)z * 131072 + idx];
    outp[idx] = s;
}

// ---------------- rn table: RMS-norm of (M[k] + bank_out[k]) ----------------
__global__ __launch_bounds__(256)
void rn_k(const float* __restrict__ Mw, const float* __restrict__ banko,
          const float* __restrict__ g, float* __restrict__ rn)
{
    int k = blockIdx.x, tid = threadIdx.x;
    __shared__ float red[256];
    float r0 = Mw[(size_t)k*512 + tid]       + banko[(size_t)k*512 + tid];
    float r1 = Mw[(size_t)k*512 + 256 + tid] + banko[(size_t)k*512 + 256 + tid];
    red[tid] = r0*r0 + r1*r1;
    __syncthreads();
    for (int s = 128; s > 0; s >>= 1) { if (tid < s) red[tid] += red[tid+s]; __syncthreads(); }
    float denom = sqrtf(red[0] * (1.0f/512.0f) + 1e-6f);
    rn[(size_t)k*512 + tid]       = r0 * (g[tid] / denom);
    rn[(size_t)k*512 + 256 + tid] = r1 * (g[256 + tid] / denom);
}

// ---------------- fused: per-row argmax + sticky mask + risky-margin flag ----------------
__device__ __forceinline__ void topflag_row(const float* __restrict__ lg, int l,
                                            u64* w, int* bpOut, int* flagOut)
{
    float v0 = lg[l], v1 = lg[64 + l], v2 = lg[128 + l], v3 = lg[192 + l];
    float bv = v0; int bp = l;
    if (v1 > bv) { bv = v1; bp = 64 + l; }
    if (v2 > bv) { bv = v2; bp = 128 + l; }
    if (v3 > bv) { bv = v3; bp = 192 + l; }
    #pragma unroll
    for (int off = 32; off; off >>= 1) {
        float ov = __shfl_xor(bv, off);
        int   op = __shfl_xor(bp, off);
        if (ov > bv || (ov == bv && op < bp)) { bv = ov; bp = op; }
    }
    float t0 = v0 + 0.1f, t1 = v1 + 0.1f, t2 = v2 + 0.1f, t3 = v3 + 0.1f;
    w[0] = __ballot((t0 > bv) || (t0 == bv && (l)       < bp));
    w[1] = __ballot((t1 > bv) || (t1 == bv && (64 + l)  < bp));
    w[2] = __ballot((t2 > bv) || (t2 == bv && (128 + l) < bp));
    w[3] = __ballot((t3 > bv) || (t3 == bv && (192 + l) < bp));
    const float D = 1e-3f;
    bool r = false;
    r |= (v0 > bv - D) && ((l)       != bp);  r |= fabsf(t0 - bv) < D;
    r |= (v1 > bv - D) && ((64 + l)  != bp);  r |= fabsf(t1 - bv) < D;
    r |= (v2 > bv - D) && ((128 + l) != bp);  r |= fabsf(t2 - bv) < D;
    r |= (v3 > bv - D) && ((192 + l) != bp);  r |= fabsf(t3 - bv) < D;
    u64 any = __ballot(r);
    *bpOut = bp;
    *flagOut = (any != 0ULL) ? 1 : 0;
}

__global__ __launch_bounds__(64)
void topflag_k(const float* __restrict__ logits, u64* __restrict__ masks,
               int* __restrict__ cArr, int* __restrict__ flags)
{
    int row = blockIdx.x, l = threadIdx.x;
    u64 w[4]; int bp, fl;
    topflag_row(logits + (size_t)row * 256, l, w, &bp, &fl);
    if (l == 0) {
        masks[(size_t)row*4 + 0] = w[0];
        masks[(size_t)row*4 + 1] = w[1];
        masks[(size_t)row*4 + 2] = w[2];
        masks[(size_t)row*4 + 3] = w[3];
        cArr[row] = bp;
        flags[row] = fl;
    }
}

// gated re-mask of only the fixed-up rows
__global__ __launch_bounds__(64)
void topflag2_k(const float* __restrict__ logits, const int* __restrict__ ridx,
                const int* __restrict__ cnt, u64* __restrict__ masks,
                int* __restrict__ cArr)
{
    int b = blockIdx.x;
    int n = *cnt; if (n > FPAD) n = FPAD;
    if (b >= n) return;
    int row = ridx[b], l = threadIdx.x;
    u64 w[4]; int bp, fl;
    topflag_row(logits + (size_t)row * 256, l, w, &bp, &fl);
    if (l == 0) {
        masks[(size_t)row*4 + 0] = w[0];
        masks[(size_t)row*4 + 1] = w[1];
        masks[(size_t)row*4 + 2] = w[2];
        masks[(size_t)row*4 + 3] = w[3];
        cArr[row] = bp;
    }
}

__global__ __launch_bounds__(256)
void compact_k(const int* __restrict__ flags, int* __restrict__ ridx, int* __restrict__ cnt)
{
    int row = blockIdx.x * 256 + threadIdx.x;
    if (row >= ROWS) return;
    if (flags[row]) {
        int p = atomicAdd(cnt, 1);
        if (p < FPAD) ridx[p] = row;
    }
}

__global__ __launch_bounds__(256)
void gatherx_k(const float* __restrict__ x, const int* __restrict__ ridx,
               const int* __restrict__ cnt, float* __restrict__ xg)
{
    int b = blockIdx.x;
    int n = *cnt; if (n > FPAD) n = FPAD;
    if (b >= n) return;
    int row = ridx[b];
    ((float4*)(xg + (size_t)b * 1024))[threadIdx.x] =
        ((const float4*)(x + (size_t)row * 1024))[threadIdx.x];
}

// ---------------- fixup reduce: h = relu(sum_z hPart + bias), cnt-gated ----------------
__global__ __launch_bounds__(256)
void redh_k(const float* __restrict__ part, const float* __restrict__ bias,
            const int* __restrict__ cnt, float* __restrict__ hg)
{
    int r = blockIdx.x;
    int n = *cnt; if (n > FPAD) n = FPAD;
    if (r >= n) return;
    int t = threadIdx.x;
    #pragma unroll
    for (int c0 = 0; c0 < HDIMD; c0 += 256) {
        int c = c0 + t;
        float s = part[(size_t)r * HDIMD + c];
        #pragma unroll
        for (int z = 1; z < KZ1; z++)
            s += part[(size_t)z * FPAD * HDIMD + (size_t)r * HDIMD + c];
        hg[(size_t)r * HDIMD + c] = fmaxf(s + bias[c], 0.f);
    }
}

// ---------------- fixup reduce: logits[ridx[b]] = sum_z lPart + bias ----------------
__global__ __launch_bounds__(256)
void redL_k(const float* __restrict__ part, const float* __restrict__ bias,
            const int* __restrict__ ridx, const int* __restrict__ cnt,
            float* __restrict__ logits)
{
    int b = blockIdx.x;
    int n = *cnt; if (n > FPAD) n = FPAD;
    if (b >= n) return;
    int t = threadIdx.x;
    float s = part[(size_t)b * KDIM + t];
    #pragma unroll
    for (int z = 1; z < KZ2; z++)
        s += part[(size_t)z * FPAD * KDIM + (size_t)b * KDIM + t];
    logits[(size_t)ridx[b] * KDIM + t] = s + bias[t];
}

// ========== parallel sticky-argmax scan: 3-phase chunked function composition ==========
__global__ __launch_bounds__(64)
void scanA_k(const u64* __restrict__ masks, const int* __restrict__ cArr,
             u32* __restrict__ chmap)   // [8*NCHK][64] u32 = 256 u8 states
{
    int blk = blockIdx.x;
    int l = threadIdx.x;
    int base = blk * 64;
    __shared__ u64 sm[64][4];
    __shared__ int sc[64];
    ulonglong2 m01 = *(const ulonglong2*)(masks + (size_t)(base + l) * 4);
    ulonglong2 m23 = *(const ulonglong2*)(masks + (size_t)(base + l) * 4 + 2);
    sm[l][0] = m01.x; sm[l][1] = m01.y; sm[l][2] = m23.x; sm[l][3] = m23.y;
    sc[l] = cArr[base + l];
    __syncthreads();

    int st[4];
    #pragma unroll
    for (int i = 0; i < 4; i++) st[i] = l * 4 + i;

    for (int j = 0; j < 64; ++j) {
        u64 w0 = sm[j][0], w1 = sm[j][1], w2 = sm[j][2], w3 = sm[j][3];
        int c = sc[j];
        #pragma unroll
        for (int i = 0; i < 4; i++) {
            int s = st[i];
            u64 wlo = (s & 64) ? w1 : w0;
            u64 whi = (s & 64) ? w3 : w2;
            u64 w   = (s & 128) ? whi : wlo;
            int stick = (int)((w >> (s & 63)) & 1ULL);
            st[i] = stick ? s : c;
        }
    }
    u32 outv = (u32)(st[0] & 255) | ((u32)(st[1] & 255) << 8)
             | ((u32)(st[2] & 255) << 16) | ((u32)(st[3] & 255) << 24);
    chmap[(size_t)blk * 64 + l] = outv;
}

__global__ __launch_bounds__(64)
void scanB_k(const u32* __restrict__ chmap, const float* __restrict__ prev_mode,
             int* __restrict__ entry)
{
    int b = blockIdx.x, l = threadIdx.x;
    __shared__ u8 lm[NCHK * 256];   // 8 KB
    const u32* src = chmap + (size_t)b * NCHK * 64;
    #pragma unroll
    for (int i = 0; i < NCHK; ++i) ((u32*)lm)[i * 64 + l] = src[i * 64 + l];

    float4 pm = ((const float4*)(prev_mode + (size_t)b * 256))[l];
    int my = -1;
    if (pm.x > 0.5f) my = l * 4 + 0;
    if (pm.y > 0.5f) my = l * 4 + 1;
    if (pm.z > 0.5f) my = l * 4 + 2;
    if (pm.w > 0.5f) my = l * 4 + 3;
    u64 bal = __ballot(my >= 0);
    int prev = 0;
    if (bal) {
        int s2 = __ffsll(bal) - 1;
        prev = __builtin_amdgcn_readlane(my, s2);
    }
    __syncthreads();
    if (l == 0) {
        int e = prev;
        for (int ci = 0; ci < NCHK; ++ci) {
            entry[b * NCHK + ci] = e;
            e = lm[ci * 256 + e];
        }
    }
}

__global__ __launch_bounds__(64)
void scanC_k(const u64* __restrict__ masks, const int* __restrict__ cArr,
             const int* __restrict__ entry, int* __restrict__ midx)
{
    int blk = blockIdx.x, l = threadIdx.x;
    int base = blk * 64;
    ulonglong2 c01 = *(const ulonglong2*)(masks + (size_t)(base + l) * 4);
    ulonglong2 c23 = *(const ulonglong2*)(masks + (size_t)(base + l) * 4 + 2);
    int cc = cArr[base + l];
    int prev = entry[blk];
    int myres = 0;
    for (int j = 0; j < 64; ++j) {
        u64 wlo = (prev & 64) ? c01.y : c01.x;
        u64 whi = (prev & 64) ? c23.y : c23.x;
        u64 w   = (prev & 128) ? whi : wlo;
        unsigned int lo32 = (unsigned int)__builtin_amdgcn_readlane((int)(unsigned int)w, j);
        unsigned int hi32 = (unsigned int)__builtin_amdgcn_readlane((int)(unsigned int)(w >> 32), j);
        int c = __builtin_amdgcn_readlane(cc, j);
        u64 ww = ((u64)hi32 << 32) | (u64)lo32;
        int stick = (int)((ww >> (prev & 63)) & 1ULL);
        prev = stick ? prev : c;
        myres = (l == j) ? prev : myres;
    }
    midx[base + l] = myres;
}

// ---------------- fused outputs: y gather + modes one-hot ----------------
__global__ __launch_bounds__(256)
void yout_k(const int* __restrict__ mode_idx, const float* __restrict__ ytab,
            float* __restrict__ y, float* __restrict__ modes)
{
    int r = blockIdx.x, t = threadIdx.x;
    int k = mode_idx[r];
    ((float4*)(y + (size_t)r * 1024))[t] =
        ((const float4*)(ytab + (size_t)k * 1024))[t];
    if (t < 64) {
        int base = t * 4;
        float4 v = make_float4(base == k ? 1.f : 0.f, base+1 == k ? 1.f : 0.f,
                               base+2 == k ? 1.f : 0.f, base+3 == k ? 1.f : 0.f);
        ((float4*)(modes + (size_t)r * 256))[t] = v;
    }
}

extern "C" void kernel_launch(void* const* d_in, const int* in_sizes, int n_in,
                              void* d_out, int out_size, void* d_ws, size_t ws_size,
                              hipStream_t stream)
{
    const float* x       = (const float*)d_in[0];
    const float* prevm   = (const float*)d_in[1];
    const float* Wtr_w   = (const float*)d_in[2];
    const float* Wtr_b   = (const float*)d_in[3];
    const float* Wms_w   = (const float*)d_in[4];
    const float* Wms_b   = (const float*)d_in[5];
    const float* Mw      = (const float*)d_in[6];
    const float* g       = (const float*)d_in[7];
    const float* Wrd_w   = (const float*)d_in[8];
    const float* Wrd_b   = (const float*)d_in[9];
    const float* bkeys   = (const float*)d_in[10];
    const float* bvals   = (const float*)d_in[11];
    const float* bused   = (const float*)d_in[12];

    float* y_out     = (float*)d_out;                       // [16384,1024]
    float* modes_out = y_out + (size_t)ROWS * DOUTD;        // [16384,256]

    char* w = (char*)d_ws;
    size_t o = 0;
    auto alloc = [&](size_t b) { size_t r = o; o = (o + b + 255) & ~(size_t)255; return r; };

    size_t oLog  = alloc((size_t)ROWS * 256 * 4);
    size_t oMask = alloc((size_t)ROWS * 32);
    size_t oCar  = alloc((size_t)ROWS * 4);
    size_t oMidx = alloc((size_t)ROWS * 4);
    size_t oInv  = alloc((size_t)BANKN * 4);
    size_t oSc   = alloc((size_t)256 * 4096 * 4);
    size_t oPB   = alloc((size_t)8 * 256 * 512 * 4);
    size_t oBo   = alloc((size_t)256 * 512 * 4);
    size_t oRn   = alloc((size_t)256 * 512 * 4);
    size_t oYt   = alloc((size_t)256 * 1024 * 4);
    size_t oW1m  = alloc((size_t)HDIMD * DIND * 2);   // Wtr^T main [2048 x 1024] f16
    size_t oW1r  = alloc((size_t)HDIMD * DIND * 2);   // Wtr^T res
    size_t oW2m  = alloc((size_t)KDIM * HDIMD * 2);   // Wms^T main [256 x 2048] f16
    size_t oW2r  = alloc((size_t)KDIM * HDIMD * 2);   // Wms^T res
    size_t oChm  = alloc((size_t)8 * NCHK * 256);     // chunk maps (u8 states)
    size_t oEnt  = alloc((size_t)8 * NCHK * 4);       // chunk entry states
    size_t oFlag = alloc((size_t)ROWS * 4);
    size_t oRidx = alloc((size_t)FPAD * 4);
    size_t oCnt  = alloc(256);
    size_t oXg   = alloc((size_t)FPAD * DIND * 4);            // 4 MB
    size_t oHP   = alloc((size_t)KZ1 * FPAD * HDIMD * 4);     // 32 MB
    size_t oHg   = alloc((size_t)FPAD * HDIMD * 4);           // 8 MB
    size_t oLP   = alloc((size_t)KZ2 * FPAD * KDIM * 4);      // 8 MB
    size_t persist = o;

    int CM = 256;
    const int cands[7] = {16384, 8192, 4096, 2048, 1024, 512, 256};
    for (int i = 0; i < 7; i++) {
        // per-row: xi 2048B + hi 4096B + part2 4096B = 10240B
        size_t need = persist + (size_t)cands[i] * 10240 + 1024;
        if (need <= ws_size) { CM = cands[i]; break; }
    }
    size_t oXi = alloc((size_t)CM * DIND * 2);
    size_t oHi = alloc((size_t)CM * HDIMD * 2);
    size_t oP2 = alloc((size_t)4 * CM * 256 * 4);

    float* logits = (float*)(w + oLog);
    u64*   masks  = (u64*)(w + oMask);
    int*   cArr   = (int*)(w + oCar);
    int*   midx   = (int*)(w + oMidx);
    float* invkn  = (float*)(w + oInv);
    float* scores = (float*)(w + oSc);
    float* partB  = (float*)(w + oPB);
    float* banko  = (float*)(w + oBo);
    float* rn     = (float*)(w + oRn);
    float* ytab   = (float*)(w + oYt);
    u16*   W1m    = (u16*)(w + oW1m);
    u16*   W1r    = (u16*)(w + oW1r);
    u16*   W2m    = (u16*)(w + oW2m);
    u16*   W2r    = (u16*)(w + oW2r);
    u32*   chmap  = (u32*)(w + oChm);
    int*   entry  = (int*)(w + oEnt);
    int*   flags  = (int*)(w + oFlag);
    int*   ridx   = (int*)(w + oRidx);
    int*   cnt    = (int*)(w + oCnt);
    float* xg     = (float*)(w + oXg);
    float* hPart  = (float*)(w + oHP);
    float* hg     = (float*)(w + oHg);
    float* lPart  = (float*)(w + oLP);
    u16*   xi     = (u16*)(w + oXi);
    u16*   hi     = (u16*)(w + oHi);
    float* part2  = (float*)(w + oP2);

    // ---- mode table pipeline (fp32, independent of front GEMMs) ----
    invkn_k<<<BANKN, 64, 0, stream>>>(bkeys, invkn);
    gemm64<true, false, false><<<dim3(64, 4, 1), 256, 0, stream>>>(Mw, bkeys, nullptr, scores,
                                                                   256, 4096, 512, 512, nullptr);
    softmax_k<<<KDIM, 256, 0, stream>>>(Mw, invkn, bused, scores);
    gemm64<false, false, false><<<dim3(8, 4, 8), 256, 0, stream>>>(scores, bvals, nullptr, partB,
                                                                   256, 512, 4096, 512, nullptr);
    redk_k<<<512, 256, 0, stream>>>(partB, banko);
    rn_k<<<KDIM, 256, 0, stream>>>(Mw, banko, g, rn);
    gemm64<false, true, false><<<dim3(16, 4, 1), 256, 0, stream>>>(rn, Wrd_w, Wrd_b, ytab,
                                                                   256, 1024, 512, 512, nullptr);

    // ---- weight split+transpose (two f16 planes each) ----
    tsplit_k<<<dim3(HDIMD / 32, DIND / 32), 256, 0, stream>>>(Wtr_w, W1m, W1r, DIND, HDIMD);
    tsplit_k<<<dim3(KDIM / 32, HDIMD / 32), 256, 0, stream>>>(Wms_w, W2m, W2r, HDIMD, KDIM);

    // ---- front GEMMs via A-main/B-split f16 MFMA ----
    for (int ch0 = 0; ch0 < ROWS; ch0 += CM) {
        long n8 = (long)CM * DIND / 8;
        packx_k<<<(int)((n8 + 255) / 256), 256, 0, stream>>>(x + (size_t)ch0 * DIND, xi, n8);
        // h = relu(x@Wtr + b), f16 out
        gemm_mfma<true><<<dim3(HDIMD / 128, CM / 128, 1), 256, 0, stream>>>(
            (const f16*)xi, (const f16*)W1m, (const f16*)W1r, Wtr_b, hi, DIND, DIND);
        // logits partials = h@Wms (split-K = 4)
        gemm_mfma<false><<<dim3(KDIM / 128, CM / 128, 4), 256, 0, stream>>>(
            (const f16*)hi, (const f16*)W2m, (const f16*)W2r, nullptr, part2, HDIMD, HDIMD / 4);
        int total4 = CM * 256 / 4;
        reduce2_k<<<(total4 + 255) / 256, 256, 0, stream>>>(part2, Wms_b,
            logits + (size_t)ch0 * 256, total4, total4, 4);
    }

    // ---- fixup: recompute risky rows in exact fp32 (split-K gemm64, cnt-gated) ----
    topflag_k<<<ROWS, 64, 0, stream>>>(logits, masks, cArr, flags);
    hipMemsetAsync(cnt, 0, 4, stream);
    compact_k<<<ROWS / 256, 256, 0, stream>>>(flags, ridx, cnt);
    gatherx_k<<<FPAD, 256, 0, stream>>>(x, ridx, cnt, xg);
    // h partials: [kz=4][FPAD x 2048]
    gemm64<false, false, false><<<dim3(HDIMD / 64, FPAD / 64, KZ1), 256, 0, stream>>>(
        xg, Wtr_w, nullptr, hPart, FPAD, HDIMD, DIND, DIND / KZ1, cnt);
    redh_k<<<FPAD, 256, 0, stream>>>(hPart, Wtr_b, cnt, hg);
    // logit partials: [kz=8][FPAD x 256]
    gemm64<false, false, false><<<dim3(KDIM / 64, FPAD / 64, KZ2), 256, 0, stream>>>(
        hg, Wms_w, nullptr, lPart, FPAD, KDIM, HDIMD, HDIMD / KZ2, cnt);
    redL_k<<<FPAD, 256, 0, stream>>>(lPart, Wms_b, ridx, cnt, logits);
    // re-mask only the fixed rows
    topflag2_k<<<FPAD, 64, 0, stream>>>(logits, ridx, cnt, masks, cArr);

    // ---- mode selection: parallel chunked scan ----
    scanA_k<<<8 * NCHK, 64, 0, stream>>>(masks, cArr, chmap);
    scanB_k<<<8, 64, 0, stream>>>(chmap, prevm, entry);
    scanC_k<<<8 * NCHK, 64, 0, stream>>>(masks, cArr, entry, midx);

    // ---- outputs ----
    yout_k<<<ROWS, 256, 0, stream>>>(midx, ytab, y_out, modes_out);
}